// Round 9
// baseline (1136.479 us; speedup 1.0000x reference)
//
#include <hip/hip_runtime.h>
#include <math.h>

#define B_  32
#define L_  256
#define PD_ 164
#define D_  240
#define H_  16
#define NB_ 6
#define NC_ 250
#define DK_ 15
#define HID_ 480
#define LP_ 257
#define KP_ 288            // keys padded to 9*32
#define SCALE_ 0.2581988897471611f   // 1/sqrt(15)
#define LOG2E_ 1.4426950408889634f

#define SMEM_ATTN (KP_*24*2 + 16*296*2 + 4*16*296*2)   // 61184 bytes

typedef __attribute__((ext_vector_type(8))) short bf16x8;
typedef __attribute__((ext_vector_type(8))) _Float16 f16x8;
typedef __attribute__((ext_vector_type(4))) float f32x4;

static __device__ inline unsigned short f2bf(float x) {
    unsigned u = __builtin_bit_cast(unsigned, x);
    u += 0x7FFFu + ((u >> 16) & 1u);     // RNE (finite values only)
    return (unsigned short)(u >> 16);
}
static __device__ inline unsigned short f2h(float x) {
    _Float16 h = (_Float16)x;
    return __builtin_bit_cast(unsigned short, h);
}
static __device__ inline void gl2lds16(const void* g, void* l) {
    __builtin_amdgcn_global_load_lds(
        (const __attribute__((address_space(1))) unsigned int*)g,
        (__attribute__((address_space(3))) unsigned int*)l, 16, 0, 0);
}

// ---- device-scope grid barrier (all blocks co-resident by construction) ----
struct Bar { unsigned cnt; unsigned gen; };

static __device__ inline void gsync(Bar* bar, unsigned nb, unsigned& target) {
    target++;
    __threadfence();                       // release: drain + make prior writes visible
    __syncthreads();
    if (threadIdx.x == 0) {
        unsigned old = __hip_atomic_fetch_add(&bar->cnt, 1u, __ATOMIC_ACQ_REL,
                                              __HIP_MEMORY_SCOPE_AGENT);
        if (old == nb - 1u) {
            __hip_atomic_store(&bar->cnt, 0u, __ATOMIC_RELAXED, __HIP_MEMORY_SCOPE_AGENT);
            __hip_atomic_store(&bar->gen, target, __ATOMIC_RELEASE, __HIP_MEMORY_SCOPE_AGENT);
        } else {
            while (__hip_atomic_load(&bar->gen, __ATOMIC_ACQUIRE,
                                     __HIP_MEMORY_SCOPE_AGENT) < target)
                __builtin_amdgcn_s_sleep(2);
        }
    }
    __syncthreads();
    __threadfence();                       // acquire: invalidate stale cache lines
}

// ============================ device phase functions =========================

static __device__ void d_mask(const float* __restrict__ x, float* __restrict__ mask) {
    for (int idx = blockIdx.x * blockDim.x + threadIdx.x; idx < B_ * LP_;
         idx += gridDim.x * blockDim.x) {
        int b = idx / LP_, l = idx % LP_;
        if (l == 0) { mask[idx] = 0.f; continue; }
        const float* xr = x + ((size_t)b * L_ + (l - 1)) * PD_;
        float mx = -1e30f;
        for (int j = 0; j < PD_; j++) mx = fmaxf(mx, xr[j]);
        mask[idx] = (mx == 0.f) ? 1.f : 0.f;
    }
}

static __device__ void d_prep_misc(const float* __restrict__ x, unsigned short* __restrict__ xbf,
                                   const float* __restrict__ bq, const float* __restrict__ bk,
                                   const float* __restrict__ bv, float* __restrict__ b720) {
    const int wave = threadIdx.x >> 6, lane = threadIdx.x & 63;
    const int nw = gridDim.x * 4;
    for (int u = blockIdx.x * 4 + wave; u < 8192 + NB_; u += nw) {
        if (u < 8192) {
            const float* src = x + (size_t)u * PD_;
            unsigned short* dst = xbf + (size_t)u * 192;
            for (int k = lane; k < 192; k += 64)
                dst[k] = f2bf(k < PD_ ? src[k] : 0.f);
        } else {
            int i = u - 8192;
            for (int n = lane; n < 720; n += 64) {
                float v = (n < 240) ? bq[i * 240 + n]
                        : (n < 480) ? bk[i * 240 + n - 240]
                                    : bv[i * 240 + n - 480];
                b720[i * 720 + n] = v;
            }
        }
    }
}

static __device__ void d_prep_weights(const float* __restrict__ e_W1, const float* __restrict__ e_W2,
                                      const float* __restrict__ Wq, const float* __restrict__ Wk,
                                      const float* __restrict__ Wv, const float* __restrict__ Wo,
                                      const float* __restrict__ W1, const float* __restrict__ W2,
                                      unsigned short* __restrict__ We1, unsigned short* __restrict__ We2,
                                      unsigned short* __restrict__ Wqkv, unsigned short* __restrict__ WoT,
                                      unsigned short* __restrict__ W1T, unsigned short* __restrict__ W2T) {
    const int wave = threadIdx.x >> 6, lane = threadIdx.x & 63;
    const int nw = gridDim.x * 4;
    for (int u = blockIdx.x * 4 + wave; u < 38 * 480; u += nw) {
        int job = u / 480, n = u - job * 480;
        const float* src; unsigned short* dst; int K, N, Kpad;
        if (job == 0)      { src = e_W1; dst = We1; K = PD_; N = 480; Kpad = 192; }
        else if (job == 1) { src = e_W2; dst = We2; K = 480; N = 240; Kpad = 480; }
        else {
            int i = (job - 2) % 6, w = (job - 2) / 6;
            if (w == 0)      { src = Wq + (size_t)i*240*240; dst = Wqkv + (size_t)i*768*256;           K=240; N=240; Kpad=256; }
            else if (w == 1) { src = Wk + (size_t)i*240*240; dst = Wqkv + (size_t)i*768*256 + 240*256; K=240; N=240; Kpad=256; }
            else if (w == 2) { src = Wv + (size_t)i*240*240; dst = Wqkv + (size_t)i*768*256 + 480*256; K=240; N=240; Kpad=256; }
            else if (w == 3) { src = Wo + (size_t)i*240*240; dst = WoT + (size_t)i*256*256;            K=240; N=240; Kpad=256; }
            else if (w == 4) { src = W1 + (size_t)i*240*480; dst = W1T + (size_t)i*512*256;            K=240; N=480; Kpad=256; }
            else             { src = W2 + (size_t)i*480*240; dst = W2T + (size_t)i*256*480;            K=480; N=240; Kpad=480; }
        }
        if (n >= N) continue;
        unsigned short* d = dst + (size_t)n * Kpad;
        for (int k = lane; k < Kpad; k += 64)
            d[k] = f2bf(k < K ? src[(size_t)k * N + n] : 0.f);
    }
}

// MFMA GEMM tile worker; tiles assigned by flat id, grid-stride.
// flags: 1 relu, 2 accumulate fp32 C, 4 QKV-packed epilogue, 8 bf16 out
template<int BN>
static __device__ void d_gemm(char* smem,
    const unsigned short* __restrict__ A, const unsigned short* __restrict__ Bt,
    const float* __restrict__ bias,
    float* __restrict__ C, unsigned short* __restrict__ Cbf,
    unsigned short* __restrict__ qp, unsigned short* __restrict__ kp,
    unsigned short* __restrict__ vp,
    int M, int N, int Kpad, int Cstride, int flags, int mTiles, int nTiles)
{
    constexpr int NJ = BN / 32;
    unsigned short* As = (unsigned short*)smem;       // 128*32
    unsigned short* Bs = As + 128 * 32;               // BN*32
    const int tid = threadIdx.x;
    const int wave = tid >> 6, lane = tid & 63;
    const int wm = (wave & 1) * 64, wn = (wave >> 1) * (BN / 2);
    const int lq = lane >> 4, lr = lane & 15;
    const int srow = lane >> 2;
    const int schk = (lane & 3) << 3;

    for (int tile = blockIdx.x; tile < mTiles * nTiles; tile += gridDim.x) {
        const int bm = (tile % mTiles) * 128;
        const int bn = (tile / mTiles) * BN;
        f32x4 acc[4][NJ];
        #pragma unroll
        for (int i = 0; i < 4; i++)
            #pragma unroll
            for (int j = 0; j < NJ; j++) acc[i][j] = (f32x4){0.f, 0.f, 0.f, 0.f};

        const unsigned short* ga0 = A + (size_t)(bm + wave * 32 + srow) * Kpad + schk;
        const unsigned short* ga1 = ga0 + (size_t)16 * Kpad;
        char* la0 = (char*)As + wave * 2048;
        char* la1 = la0 + 1024;
        const unsigned short* gb0, *gb1 = nullptr;
        char *lb0, *lb1 = nullptr;
        if constexpr (BN == 64) {
            gb0 = Bt + (size_t)(bn + wave * 16 + srow) * Kpad + schk;
            lb0 = (char*)Bs + wave * 1024;
        } else {
            gb0 = Bt + (size_t)(bn + wave * 32 + srow) * Kpad + schk;
            gb1 = gb0 + (size_t)16 * Kpad;
            lb0 = (char*)Bs + wave * 2048;
            lb1 = lb0 + 1024;
        }

        const int nkt = Kpad >> 5;
        for (int kt = 0; kt < nkt; kt++) {
            gl2lds16(ga0, la0);
            gl2lds16(ga1, la1);
            gl2lds16(gb0, lb0);
            if constexpr (BN == 128) gl2lds16(gb1, lb1);
            ga0 += 32; ga1 += 32; gb0 += 32;
            if constexpr (BN == 128) gb1 += 32;
            __syncthreads();
            bf16x8 af[4], bfr[NJ];
            #pragma unroll
            for (int i = 0; i < 4; i++)
                af[i] = *(const bf16x8*)&As[(wm + i * 16 + lr) * 32 + lq * 8];
            #pragma unroll
            for (int j = 0; j < NJ; j++)
                bfr[j] = *(const bf16x8*)&Bs[(wn + j * 16 + lr) * 32 + lq * 8];
            #pragma unroll
            for (int i = 0; i < 4; i++)
                #pragma unroll
                for (int j = 0; j < NJ; j++)
                    acc[i][j] = __builtin_amdgcn_mfma_f32_16x16x32_bf16(af[i], bfr[j], acc[i][j], 0, 0, 0);
            __syncthreads();
        }

        if (flags & 4) {                       // QKV packed epilogue (N=720)
            #pragma unroll
            for (int j = 0; j < NJ; j++) {
                int n = bn + wn + j * 16 + lr;
                if (n >= N) continue;
                int which = n / 240;
                int rem = n - which * 240;
                int hh = rem / 15;
                int c = rem - hh * 15;
                unsigned short* dst = (which == 0) ? qp : (which == 1) ? kp : vp;
                float bias_n = bias[n];
                float mult = (which == 0) ? (SCALE_ * LOG2E_) : 1.f;
                #pragma unroll
                for (int i = 0; i < 4; i++)
                    #pragma unroll
                    for (int r = 0; r < 4; r++) {
                        int m = bm + wm + i * 16 + lq * 4 + r;
                        if (m >= M) continue;
                        float s = (acc[i][j][r] + bias_n) * mult;
                        int b = m / LP_, l = m - b * LP_;
                        unsigned short bits = (which == 2) ? f2h(s) : f2bf(s);
                        dst[(((size_t)b * H_ + hh) * LP_ + l) * 16 + c] = bits;
                    }
            }
        } else if (flags & 8) {                // bf16 output
            #pragma unroll
            for (int i = 0; i < 4; i++)
                #pragma unroll
                for (int j = 0; j < NJ; j++) {
                    int n = bn + wn + j * 16 + lr;
                    if (n >= N) continue;
                    float bias_n = bias ? bias[n] : 0.f;
                    #pragma unroll
                    for (int r = 0; r < 4; r++) {
                        int m = bm + wm + i * 16 + lq * 4 + r;
                        if (m >= M) continue;
                        float s = acc[i][j][r] + bias_n;
                        if (flags & 1) s = fmaxf(s, 0.f);
                        Cbf[(size_t)m * Cstride + n] = f2bf(s);
                    }
                }
        } else {                               // fp32 output (optionally accumulate)
            #pragma unroll
            for (int i = 0; i < 4; i++)
                #pragma unroll
                for (int j = 0; j < NJ; j++) {
                    int n = bn + wn + j * 16 + lr;
                    if (n >= N) continue;
                    float bias_n = bias ? bias[n] : 0.f;
                    #pragma unroll
                    for (int r = 0; r < 4; r++) {
                        int m = bm + wm + i * 16 + lq * 4 + r;
                        if (m >= M) continue;
                        float s = acc[i][j][r] + bias_n;
                        if (flags & 1) s = fmaxf(s, 0.f);
                        size_t off = (size_t)m * Cstride + n;
                        if (flags & 2) C[off] += s; else C[off] = s;
                    }
                }
        }
    }
}

static __device__ void d_ln240(const float* __restrict__ in, unsigned short* __restrict__ out,
                               const float* __restrict__ g, const float* __restrict__ bb) {
    const int wave = threadIdx.x >> 6, lane = threadIdx.x & 63;
    const int nw = gridDim.x * 4;
    for (int row = blockIdx.x * 4 + wave; row < B_ * LP_; row += nw) {
        const float* x = in + (size_t)row * 240;
        float4 v = {0.f, 0.f, 0.f, 0.f};
        if (lane < 60) v = *(const float4*)(x + lane * 4);
        float s = (v.x + v.y) + (v.z + v.w);
        #pragma unroll
        for (int off = 32; off; off >>= 1) s += __shfl_xor(s, off);
        const float mean = s * (1.f / 240.f);
        float4 d;
        d.x = v.x - mean; d.y = v.y - mean; d.z = v.z - mean; d.w = v.w - mean;
        float vs = (lane < 60) ? (d.x * d.x + d.y * d.y) + (d.z * d.z + d.w * d.w) : 0.f;
        #pragma unroll
        for (int off = 32; off; off >>= 1) vs += __shfl_xor(vs, off);
        const float rs = rsqrtf(vs * (1.f / 240.f) + 1e-5f);
        ushort4 o4 = {0, 0, 0, 0};
        if (lane < 60) {
            float4 g4 = *(const float4*)(g + lane * 4);
            float4 b4 = *(const float4*)(bb + lane * 4);
            o4.x = f2bf(d.x * rs * g4.x + b4.x);
            o4.y = f2bf(d.y * rs * g4.y + b4.y);
            o4.z = f2bf(d.z * rs * g4.z + b4.z);
            o4.w = f2bf(d.w * rs * g4.w + b4.w);
        }
        *(ushort4*)(out + (size_t)row * 256 + lane * 4) = o4;
    }
}

static __device__ void d_ln480(const float* __restrict__ in, unsigned short* __restrict__ out,
                               const float* __restrict__ g, const float* __restrict__ bb) {
    const int wave = threadIdx.x >> 6, lane = threadIdx.x & 63;
    const int nw = gridDim.x * 4;
    for (int row = blockIdx.x * 4 + wave; row < 8192; row += nw) {
        const float* x = in + (size_t)row * 480;
        float4 va = {0.f,0.f,0.f,0.f}, vb = {0.f,0.f,0.f,0.f};
        if (lane < 60) {
            va = *(const float4*)(x + lane * 8);
            vb = *(const float4*)(x + lane * 8 + 4);
        }
        float s = ((va.x + va.y) + (va.z + va.w)) + ((vb.x + vb.y) + (vb.z + vb.w));
        #pragma unroll
        for (int off = 32; off; off >>= 1) s += __shfl_xor(s, off);
        const float mean = s * (1.f / 480.f);
        float4 da, db;
        da.x = va.x - mean; da.y = va.y - mean; da.z = va.z - mean; da.w = va.w - mean;
        db.x = vb.x - mean; db.y = vb.y - mean; db.z = vb.z - mean; db.w = vb.w - mean;
        float vs = (lane < 60) ? ((da.x*da.x + da.y*da.y) + (da.z*da.z + da.w*da.w)) +
                                 ((db.x*db.x + db.y*db.y) + (db.z*db.z + db.w*db.w)) : 0.f;
        #pragma unroll
        for (int off = 32; off; off >>= 1) vs += __shfl_xor(vs, off);
        const float rs = rsqrtf(vs * (1.f / 480.f) + 1e-5f);
        if (lane < 60) {
            float4 ga = *(const float4*)(g + lane * 8);
            float4 gb = *(const float4*)(g + lane * 8 + 4);
            float4 ba = *(const float4*)(bb + lane * 8);
            float4 b2 = *(const float4*)(bb + lane * 8 + 4);
            ushort4 oa, ob;
            oa.x = f2bf(fmaxf(da.x * rs * ga.x + ba.x, 0.f));
            oa.y = f2bf(fmaxf(da.y * rs * ga.y + ba.y, 0.f));
            oa.z = f2bf(fmaxf(da.z * rs * ga.z + ba.z, 0.f));
            oa.w = f2bf(fmaxf(da.w * rs * ga.w + ba.w, 0.f));
            ob.x = f2bf(fmaxf(db.x * rs * gb.x + b2.x, 0.f));
            ob.y = f2bf(fmaxf(db.y * rs * gb.y + b2.y, 0.f));
            ob.z = f2bf(fmaxf(db.z * rs * gb.z + b2.z, 0.f));
            ob.w = f2bf(fmaxf(db.w * rs * gb.w + b2.w, 0.f));
            *(ushort4*)(out + (size_t)row * 480 + lane * 8) = oa;
            *(ushort4*)(out + (size_t)row * 480 + lane * 8 + 4) = ob;
        }
    }
}

static __device__ void d_embed_finish(const float* __restrict__ tmp, const float* __restrict__ mask,
                                      const float* __restrict__ g, const float* __restrict__ bb,
                                      const float* __restrict__ pos, const float* __restrict__ cls,
                                      float* __restrict__ h,
                                      unsigned short* __restrict__ qp, unsigned short* __restrict__ kp,
                                      unsigned short* __restrict__ vp) {
    const int wave = threadIdx.x >> 6, lane = threadIdx.x & 63;
    const int nw = gridDim.x * 4;
    for (int row = blockIdx.x * 4 + wave; row < B_ * LP_; row += nw) {
        const int b = row / LP_, l = row - b * LP_;
        float* outr = h + (size_t)row * 240;

        if (lane >= 60 && lane <= 62) {
            unsigned short bits;
            unsigned short* dst;
            if (lane == 60) { bits = f2bf(LOG2E_); dst = qp; }
            else if (lane == 61) { bits = (mask[row] != 0.f) ? f2bf(-10000.f) : 0; dst = kp; }
            else { bits = f2h(1.f); dst = vp; }
            #pragma unroll
            for (int hh = 0; hh < H_; hh++)
                dst[(((size_t)b * H_ + hh) * LP_ + l) * 16 + 15] = bits;
        }

        if (l == 0) {
            if (lane < 60) *(float4*)(outr + lane * 4) = *(const float4*)(cls + lane * 4);
            continue;
        }
        const float* x = tmp + ((size_t)b * L_ + (l - 1)) * 240;
        float4 v = {0.f, 0.f, 0.f, 0.f};
        if (lane < 60) v = *(const float4*)(x + lane * 4);
        float s = (v.x + v.y) + (v.z + v.w);
        #pragma unroll
        for (int off = 32; off; off >>= 1) s += __shfl_xor(s, off);
        const float mean = s * (1.f / 240.f);
        float4 d;
        d.x = v.x - mean; d.y = v.y - mean; d.z = v.z - mean; d.w = v.w - mean;
        float vs = (lane < 60) ? (d.x * d.x + d.y * d.y) + (d.z * d.z + d.w * d.w) : 0.f;
        #pragma unroll
        for (int off = 32; off; off >>= 1) vs += __shfl_xor(vs, off);
        const float rs = rsqrtf(vs * (1.f / 240.f) + 1e-5f);
        if (lane < 60) {
            float4 g4 = *(const float4*)(g + lane * 4);
            float4 b4 = *(const float4*)(bb + lane * 4);
            float4 p4 = *(const float4*)(pos + (size_t)(l - 1) * 240 + lane * 4);
            float4 o;
            o.x = fmaxf(d.x * rs * g4.x + b4.x, 0.f) + p4.x;
            o.y = fmaxf(d.y * rs * g4.y + b4.y, 0.f) + p4.y;
            o.z = fmaxf(d.z * rs * g4.z + b4.z, 0.f) + p4.z;
            o.w = fmaxf(d.w * rs * g4.w + b4.w, 0.f) + p4.w;
            *(float4*)(outr + lane * 4) = o;
        }
    }
}

static __device__ void d_attn(char* smem,
                              const unsigned short* __restrict__ qp, const unsigned short* __restrict__ kp,
                              const unsigned short* __restrict__ vp, unsigned short* __restrict__ obf) {
    unsigned short* Kl = (unsigned short*)smem;       // KP_*24
    unsigned short* Vt = Kl + KP_ * 24;               // 16*296
    unsigned short* Pl = Vt + 16 * 296;               // 4*16*296
    const int tid = threadIdx.x;
    const int wave = tid >> 6, lane = tid & 63;
    const int lq = lane >> 4, lr = lane & 15;

    for (int u = blockIdx.x; u < H_ * B_; u += gridDim.x) {
        const int hh = u & 15, b = u >> 4;
        const size_t base = ((size_t)b * H_ + hh) * LP_ * 16;

        for (int key = tid; key < KP_; key += 256) {
            uint4 z = {0u, 0u, 0u, 0u};
            uint4 k0 = z, k1 = z, v0 = z, v1 = z;
            if (key < LP_) {
                k0 = *(const uint4*)(kp + base + (size_t)key * 16);
                k1 = *(const uint4*)(kp + base + (size_t)key * 16 + 8);
                v0 = *(const uint4*)(vp + base + (size_t)key * 16);
                v1 = *(const uint4*)(vp + base + (size_t)key * 16 + 8);
            } else {
                k1.w = 0xC61C0000u;            // elem15 = bf16(-10000) sentinel
            }
            *(uint4*)&Kl[key * 24] = k0;
            *(uint4*)&Kl[key * 24 + 8] = k1;
            unsigned short vs[8];
            *(uint4*)vs = v0;
            #pragma unroll
            for (int d = 0; d < 8; d++) Vt[d * 296 + key] = vs[d];
            *(uint4*)vs = v1;
            #pragma unroll
            for (int d = 0; d < 8; d++) Vt[(d + 8) * 296 + key] = vs[d];
        }
        __syncthreads();

        unsigned short* Pw = &Pl[wave * 16 * 296];
        for (int qt = wave; qt < 17; qt += 4) {
            const int qrow = qt * 16 + lr;
            bf16x8 aq = {0, 0, 0, 0, 0, 0, 0, 0};
            if (lq < 2)
                aq = *(const bf16x8*)(qp + base + (size_t)qrow * 16 + lq * 8);
            for (int kt = 0; kt < 18; kt++) {
                bf16x8 bk = {0, 0, 0, 0, 0, 0, 0, 0};
                if (lq < 2)
                    bk = *(const bf16x8*)&Kl[(kt * 16 + lr) * 24 + lq * 8];
                f32x4 sacc = {0.f, 0.f, 0.f, 0.f};
                sacc = __builtin_amdgcn_mfma_f32_16x16x32_bf16(aq, bk, sacc, 0, 0, 0);
                #pragma unroll
                for (int r = 0; r < 4; r++)
                    Pw[(lq * 4 + r) * 296 + kt * 16 + lr] = f2h(exp2f(sacc[r]));
            }
            asm volatile("s_waitcnt lgkmcnt(0)" ::: "memory");
            f32x4 o = {0.f, 0.f, 0.f, 0.f};
            #pragma unroll
            for (int ks = 0; ks < 9; ks++) {
                f16x8 ap = *(const f16x8*)&Pw[lr * 296 + ks * 32 + lq * 8];
                f16x8 bv = *(const f16x8*)&Vt[lr * 296 + ks * 32 + lq * 8];
                o = __builtin_amdgcn_mfma_f32_16x16x32_f16(ap, bv, o, 0, 0, 0);
            }
            asm volatile("s_waitcnt lgkmcnt(0)" ::: "memory");
            #pragma unroll
            for (int r = 0; r < 4; r++) {
                float denom = __shfl(o[r], lane | 15);
                int q = qt * 16 + lq * 4 + r;
                if (q < LP_ && lr < 15)
                    obf[((size_t)b * LP_ + q) * 256 + hh * DK_ + lr] = f2bf(o[r] / denom);
            }
        }
        if (hh == 0) {
            for (int q = tid; q < LP_; q += 256) {
                uint4 z = {0u, 0u, 0u, 0u};
                *(uint4*)(obf + ((size_t)b * LP_ + q) * 256 + 240) = z;
                *(uint4*)(obf + ((size_t)b * LP_ + q) * 256 + 248) = z;
            }
        }
        __syncthreads();
    }
}

static __device__ void d_pool_partial(const float* __restrict__ h, const float* __restrict__ mask,
                                      float* __restrict__ partial) {
    for (int u = blockIdx.x; u < B_ * 9; u += gridDim.x) {
        int b = u & 31, slice = u >> 5;
        int d = threadIdx.x;
        if (d >= D_) continue;
        float s = 0.f;
        int l0 = slice * 29;
        for (int i = 0; i < 29; i++) {
            int l = l0 + i;
            if (l < LP_ && mask[b * LP_ + l] == 0.f)
                s += h[((size_t)b * LP_ + l) * D_ + d];
        }
        partial[((size_t)b * 9 + slice) * D_ + d] = s;
    }
}

static __device__ void d_pool_logits(char* smem,
                                     const float* __restrict__ partial, const float* __restrict__ mask,
                                     const float* __restrict__ W, const float* __restrict__ bias,
                                     float* __restrict__ out) {
    float* red = (float*)smem;           // 256
    float* pool = red + 256;             // 240
    for (int b = blockIdx.x; b < B_; b += gridDim.x) {
        int t = threadIdx.x;
        float c = 0.f;
        for (int l = t; l < LP_; l += 256) c += (mask[b * LP_ + l] == 0.f) ? 1.f : 0.f;
        red[t] = c;
        __syncthreads();
        for (int off = 128; off > 0; off >>= 1) {
            if (t < off) red[t] += red[t + off];
            __syncthreads();
        }
        float inv = 1.f / red[0];
        if (t < D_) {
            float s = 0.f;
            #pragma unroll
            for (int sl = 0; sl < 9; sl++) s += partial[((size_t)b * 9 + sl) * D_ + t];
            pool[t] = s * inv;
        }
        __syncthreads();
        if (t < NC_) {
            float s = bias[t];
            for (int kk = 0; kk < D_; kk++) s += pool[kk] * W[(size_t)kk * NC_ + t];
            out[b * NC_ + t] = s;
        }
        __syncthreads();
    }
}

// ============================ mega persistent kernel =========================

struct MArgs {
    const float *x, *pos, *cls;
    const float *e_W1, *e_b1, *e_g1, *e_bn1, *e_W2, *e_b2, *e_g2, *e_bn2;
    const float *ln1_g, *ln1_b, *ln2_g, *ln2_b;
    const float *Wq, *bq, *Wk, *bk, *Wv, *bv, *Wo, *bo;
    const float *W1, *b1, *W2, *b2, *logit_W, *logit_b;
    float *mask, *h, *b720, *part, *tmp1, *y32, *out;
    unsigned short *xbf, *We1, *We2, *Wqkv, *WoT, *W1T, *W2T;
    unsigned short *tbf, *ybf, *obf, *qp, *kp, *vp, *t480;
    Bar* bar;
    unsigned nb;
};

__global__ __launch_bounds__(256, 2) void mega(MArgs a) {
    __shared__ __align__(16) char smem[SMEM_ATTN];
    unsigned tg = 0;
    const unsigned nb = a.nb;

    d_mask(a.x, a.mask);
    d_prep_misc(a.x, a.xbf, a.bq, a.bk, a.bv, a.b720);
    d_prep_weights(a.e_W1, a.e_W2, a.Wq, a.Wk, a.Wv, a.Wo, a.W1, a.W2,
                   a.We1, a.We2, a.Wqkv, a.WoT, a.W1T, a.W2T);
    gsync(a.bar, nb, tg);
    d_gemm<128>(smem, a.xbf, a.We1, a.e_b1, a.tmp1, nullptr, nullptr, nullptr, nullptr,
                8192, 480, 192, 480, 0, 64, 4);
    gsync(a.bar, nb, tg);
    d_ln480(a.tmp1, a.t480, a.e_g1, a.e_bn1);
    gsync(a.bar, nb, tg);
    d_gemm<64>(smem, a.t480, a.We2, a.e_b2, a.y32, nullptr, nullptr, nullptr, nullptr,
               8192, 240, 480, 240, 0, 64, 4);
    gsync(a.bar, nb, tg);
    d_embed_finish(a.y32, a.mask, a.e_g2, a.e_bn2, a.pos, a.cls, a.h, a.qp, a.kp, a.vp);
    gsync(a.bar, nb, tg);

    for (int i = 0; i < NB_; i++) {
        d_ln240(a.h, a.ybf, a.ln1_g + i * D_, a.ln1_b + i * D_);
        gsync(a.bar, nb, tg);
        d_gemm<128>(smem, a.ybf, a.Wqkv + (size_t)i * 768 * 256, a.b720 + i * 720,
                    nullptr, nullptr, a.qp, a.kp, a.vp,
                    B_ * LP_, 720, 256, 0, 4, 65, 6);
        gsync(a.bar, nb, tg);
        d_attn(smem, a.qp, a.kp, a.vp, a.obf);
        gsync(a.bar, nb, tg);
        d_gemm<64>(smem, a.obf, a.WoT + (size_t)i * 256 * 256, a.bo + i * D_,
                   a.h, nullptr, nullptr, nullptr, nullptr,
                   B_ * LP_, 240, 256, 240, 2, 65, 4);
        gsync(a.bar, nb, tg);
        d_ln240(a.h, a.ybf, a.ln2_g + i * D_, a.ln2_b + i * D_);
        gsync(a.bar, nb, tg);
        d_gemm<128>(smem, a.ybf, a.W1T + (size_t)i * 512 * 256, a.b1 + i * HID_,
                    nullptr, a.tbf, nullptr, nullptr, nullptr,
                    B_ * LP_, 480, 256, 480, 1 | 8, 65, 4);
        gsync(a.bar, nb, tg);
        d_gemm<64>(smem, a.tbf, a.W2T + (size_t)i * 256 * 480, a.b2 + i * D_,
                   a.h, nullptr, nullptr, nullptr, nullptr,
                   B_ * LP_, 240, 480, 240, 2, 65, 4);
        gsync(a.bar, nb, tg);
    }

    d_pool_partial(a.h, a.mask, a.part);
    gsync(a.bar, nb, tg);
    d_pool_logits(smem, a.part, a.mask, a.logit_W, a.logit_b, a.out);
}

// ============================ fallback wrapper kernels =======================

__global__ void k_mask(const float* x, float* mask) { d_mask(x, mask); }
__global__ void k_prep_misc(const float* x, unsigned short* xbf, const float* bq,
                            const float* bk, const float* bv, float* b720) {
    d_prep_misc(x, xbf, bq, bk, bv, b720);
}
__global__ void k_prep_weights(const float* e_W1, const float* e_W2, const float* Wq,
                               const float* Wk, const float* Wv, const float* Wo,
                               const float* W1, const float* W2,
                               unsigned short* We1, unsigned short* We2, unsigned short* Wqkv,
                               unsigned short* WoT, unsigned short* W1T, unsigned short* W2T) {
    d_prep_weights(e_W1, e_W2, Wq, Wk, Wv, Wo, W1, W2, We1, We2, Wqkv, WoT, W1T, W2T);
}
template<int BN>
__global__ __launch_bounds__(256) void k_gemm(const unsigned short* A, const unsigned short* Bt,
                                              const float* bias, float* C, unsigned short* Cbf,
                                              unsigned short* qp, unsigned short* kp, unsigned short* vp,
                                              int M, int N, int Kpad, int Cstride, int flags,
                                              int mTiles, int nTiles) {
    __shared__ __align__(16) char smem[128 * 32 * 2 + BN * 32 * 2];
    d_gemm<BN>(smem, A, Bt, bias, C, Cbf, qp, kp, vp, M, N, Kpad, Cstride, flags, mTiles, nTiles);
}
__global__ __launch_bounds__(256) void k_ln240(const float* in, unsigned short* out,
                                               const float* g, const float* bb) {
    d_ln240(in, out, g, bb);
}
__global__ __launch_bounds__(256) void k_ln480(const float* in, unsigned short* out,
                                               const float* g, const float* bb) {
    d_ln480(in, out, g, bb);
}
__global__ __launch_bounds__(256) void k_embed_finish(const float* tmp, const float* mask,
                                                      const float* g, const float* bb,
                                                      const float* pos, const float* cls, float* h,
                                                      unsigned short* qp, unsigned short* kp,
                                                      unsigned short* vp) {
    d_embed_finish(tmp, mask, g, bb, pos, cls, h, qp, kp, vp);
}
__global__ __launch_bounds__(256) void k_attn(const unsigned short* qp, const unsigned short* kp,
                                              const unsigned short* vp, unsigned short* obf) {
    __shared__ __align__(16) char smem[SMEM_ATTN];
    d_attn(smem, qp, kp, vp, obf);
}
__global__ void k_pool_partial(const float* h, const float* mask, float* partial) {
    d_pool_partial(h, mask, partial);
}
__global__ __launch_bounds__(256) void k_pool_logits(const float* partial, const float* mask,
                                                     const float* W, const float* bias, float* out) {
    __shared__ __align__(16) char smem[2048];
    d_pool_logits(smem, partial, mask, W, bias, out);
}

// ============================ host launch ====================================

extern "C" void kernel_launch(void* const* d_in, const int* in_sizes, int n_in,
                              void* d_out, int out_size, void* d_ws, size_t ws_size,
                              hipStream_t stream) {
    const float* x        = (const float*)d_in[0];
    const float* pos      = (const float*)d_in[1];
    const float* cls      = (const float*)d_in[2];
    const float* e_W1     = (const float*)d_in[3];
    const float* e_b1     = (const float*)d_in[4];
    const float* e_g1     = (const float*)d_in[5];
    const float* e_bn1    = (const float*)d_in[6];
    const float* e_W2     = (const float*)d_in[7];
    const float* e_b2     = (const float*)d_in[8];
    const float* e_g2     = (const float*)d_in[9];
    const float* e_bn2    = (const float*)d_in[10];
    const float* ln1_g    = (const float*)d_in[11];
    const float* ln1_b    = (const float*)d_in[12];
    const float* Wq       = (const float*)d_in[13];
    const float* bq       = (const float*)d_in[14];
    const float* Wk       = (const float*)d_in[15];
    const float* bk       = (const float*)d_in[16];
    const float* Wv       = (const float*)d_in[17];
    const float* bv       = (const float*)d_in[18];
    const float* Wo       = (const float*)d_in[19];
    const float* bo       = (const float*)d_in[20];
    const float* ln2_g    = (const float*)d_in[21];
    const float* ln2_b    = (const float*)d_in[22];
    const float* W1       = (const float*)d_in[23];
    const float* b1       = (const float*)d_in[24];
    const float* W2       = (const float*)d_in[25];
    const float* b2       = (const float*)d_in[26];
    const float* logit_W  = (const float*)d_in[27];
    const float* logit_b  = (const float*)d_in[28];
    float* out = (float*)d_out;

    const size_t TOK  = (size_t)B_ * LP_;            // 8224
    const size_t TOKP = 8320;                        // padded to 65*128
    const size_t HN   = TOK * D_;
    const size_t QN   = (size_t)B_ * H_ * LP_ * 16;  // 2,105,344

    char* wsb = (char*)d_ws;
    size_t cur = 0;
    auto take = [&](size_t bytes) { void* p = wsb + cur; cur += (bytes + 127) & ~127ULL; return p; };
    Bar* bar    = (Bar*)take(128);
    float* mask = (float*)take(8224 * 4);
    float* h    = (float*)take(HN * 4);
    float* b720 = (float*)take(NB_ * 720 * 4);
    float* part = (float*)take((size_t)B_ * 9 * D_ * 4);
    void* regionA = take((size_t)8192 * 480 * 4);
    float* tmp1 = (float*)regionA;
    unsigned short* tbf = (unsigned short*)regionA;
    void* regionB = take(TOKP * 256 * 2 * 2);
    float* y32 = (float*)regionB;
    unsigned short* ybf = (unsigned short*)regionB;
    unsigned short* obf = ybf + TOKP * 256;
    unsigned short* xbf  = (unsigned short*)take((size_t)8192 * 192 * 2);
    unsigned short* We1  = (unsigned short*)take((size_t)512 * 192 * 2);
    unsigned short* We2  = (unsigned short*)take((size_t)256 * 480 * 2);
    unsigned short* Wqkv = (unsigned short*)take((size_t)NB_ * 768 * 256 * 2);
    unsigned short* WoT  = (unsigned short*)take((size_t)NB_ * 256 * 256 * 2);
    unsigned short* W1T  = (unsigned short*)take((size_t)NB_ * 512 * 256 * 2);
    unsigned short* W2T  = (unsigned short*)take((size_t)NB_ * 256 * 480 * 2);
    unsigned short* qp = (unsigned short*)take(QN * 3 * 2 + 16 * 16 * 2);
    unsigned short* kp = qp + QN;
    unsigned short* vp = kp + QN;
    unsigned short* t480 = qp;   // aliases qp/kp, dead before embed_finish

    // grid size from occupancy (host-only query; capture-safe)
    int occ = 0;
    hipError_t oe = hipOccupancyMaxActiveBlocksPerMultiprocessor(&occ, (const void*)mega, 256, 0);
    int nb = (oe == hipSuccess) ? occ * 256 : 0;
    if (nb > 512) nb = 512;

    if (nb >= 128) {
        MArgs ma;
        ma.x = x; ma.pos = pos; ma.cls = cls;
        ma.e_W1 = e_W1; ma.e_b1 = e_b1; ma.e_g1 = e_g1; ma.e_bn1 = e_bn1;
        ma.e_W2 = e_W2; ma.e_b2 = e_b2; ma.e_g2 = e_g2; ma.e_bn2 = e_bn2;
        ma.ln1_g = ln1_g; ma.ln1_b = ln1_b; ma.ln2_g = ln2_g; ma.ln2_b = ln2_b;
        ma.Wq = Wq; ma.bq = bq; ma.Wk = Wk; ma.bk = bk; ma.Wv = Wv; ma.bv = bv;
        ma.Wo = Wo; ma.bo = bo; ma.W1 = W1; ma.b1 = b1; ma.W2 = W2; ma.b2 = b2;
        ma.logit_W = logit_W; ma.logit_b = logit_b;
        ma.mask = mask; ma.h = h; ma.b720 = b720; ma.part = part;
        ma.tmp1 = tmp1; ma.y32 = y32; ma.out = out;
        ma.xbf = xbf; ma.We1 = We1; ma.We2 = We2; ma.Wqkv = Wqkv;
        ma.WoT = WoT; ma.W1T = W1T; ma.W2T = W2T;
        ma.tbf = tbf; ma.ybf = ybf; ma.obf = obf;
        ma.qp = qp; ma.kp = kp; ma.vp = vp; ma.t480 = t480;
        ma.bar = bar; ma.nb = (unsigned)nb;

        hipMemsetAsync(bar, 0, sizeof(Bar), stream);
        mega<<<nb, 256, 0, stream>>>(ma);
        return;
    }

    // ---------------- fallback: separate kernels (same work) ----------------
    const int BS = 256;
    k_mask<<<33, BS, 0, stream>>>(x, mask);
    k_prep_misc<<<2050, BS, 0, stream>>>(x, xbf, bq, bk, bv, b720);
    k_prep_weights<<<4560, BS, 0, stream>>>(e_W1, e_W2, Wq, Wk, Wv, Wo, W1, W2,
                                            We1, We2, Wqkv, WoT, W1T, W2T);
    k_gemm<128><<<256, BS, 0, stream>>>(xbf, We1, e_b1, tmp1, nullptr, nullptr, nullptr, nullptr,
                                        8192, 480, 192, 480, 0, 64, 4);
    k_ln480<<<2048, BS, 0, stream>>>(tmp1, t480, e_g1, e_bn1);
    k_gemm<64><<<256, BS, 0, stream>>>(t480, We2, e_b2, y32, nullptr, nullptr, nullptr, nullptr,
                                       8192, 240, 480, 240, 0, 64, 4);
    k_embed_finish<<<2056, BS, 0, stream>>>(y32, mask, e_g2, e_bn2, pos, cls, h, qp, kp, vp);
    for (int i = 0; i < NB_; i++) {
        k_ln240<<<2056, BS, 0, stream>>>(h, ybf, ln1_g + i * D_, ln1_b + i * D_);
        k_gemm<128><<<390, BS, 0, stream>>>(ybf, Wqkv + (size_t)i * 768 * 256, b720 + i * 720,
                                            nullptr, nullptr, qp, kp, vp,
                                            (int)TOK, 720, 256, 0, 4, 65, 6);
        k_attn<<<512, BS, 0, stream>>>(qp, kp, vp, obf);
        k_gemm<64><<<260, BS, 0, stream>>>(obf, WoT + (size_t)i * 256 * 256, bo + i * D_,
                                           h, nullptr, nullptr, nullptr, nullptr,
                                           (int)TOK, 240, 256, 240, 2, 65, 4);
        k_ln240<<<2056, BS, 0, stream>>>(h, ybf, ln2_g + i * D_, ln2_b + i * D_);
        k_gemm<128><<<260, BS, 0, stream>>>(ybf, W1T + (size_t)i * 512 * 256, b1 + i * HID_,
                                            nullptr, tbf, nullptr, nullptr, nullptr,
                                            (int)TOK, 480, 256, 480, 1 | 8, 65, 4);
        k_gemm<64><<<260, BS, 0, stream>>>(tbf, W2T + (size_t)i * 256 * 480, b2 + i * D_,
                                           h, nullptr, nullptr, nullptr, nullptr,
                                           (int)TOK, 240, 480, 240, 2, 65, 4);
    }
    k_pool_partial<<<288, BS, 0, stream>>>(h, mask, part);
    k_pool_logits<<<32, BS, 0, stream>>>(part, mask, logit_W, logit_b, out);
}

// Round 10
// 1049.017 us; speedup vs baseline: 1.0834x; 1.0834x over previous
//
#include <hip/hip_runtime.h>
#include <math.h>

#define B_  32
#define L_  256
#define PD_ 164
#define D_  240
#define H_  16
#define NB_ 6
#define NC_ 250
#define DK_ 15
#define HID_ 480
#define LP_ 257
#define KP_ 288            // keys padded to 9*32
#define SCALE_ 0.2581988897471611f   // 1/sqrt(15)
#define LOG2E_ 1.4426950408889634f

typedef __attribute__((ext_vector_type(8))) short bf16x8;
typedef __attribute__((ext_vector_type(8))) _Float16 f16x8;
typedef __attribute__((ext_vector_type(4))) float f32x4;

static __device__ inline unsigned short f2bf(float x) {
    unsigned u = __builtin_bit_cast(unsigned, x);
    u += 0x7FFFu + ((u >> 16) & 1u);     // RNE (finite values only)
    return (unsigned short)(u >> 16);
}
static __device__ inline unsigned short f2h(float x) {
    _Float16 h = (_Float16)x;
    return __builtin_bit_cast(unsigned short, h);
}

// async global->LDS, 16B per lane; lds dest must be wave-uniform base (+lane*16)
static __device__ inline void gl2lds16(const void* g, void* l) {
    __builtin_amdgcn_global_load_lds(
        (const __attribute__((address_space(1))) unsigned int*)g,
        (__attribute__((address_space(3))) unsigned int*)l, 16, 0, 0);
}

// ---------------- mask ----------------
__global__ void mask_kernel(const float* __restrict__ x, float* __restrict__ mask) {
    int idx = blockIdx.x * blockDim.x + threadIdx.x;
    if (idx >= B_ * LP_) return;
    int b = idx / LP_, l = idx % LP_;
    if (l == 0) { mask[idx] = 0.f; return; }
    const float* xr = x + ((size_t)b * L_ + (l - 1)) * PD_;
    float mx = -1e30f;
    for (int j = 0; j < PD_; j++) mx = fmaxf(mx, xr[j]);
    mask[idx] = (mx == 0.f) ? 1.f : 0.f;
}

// --------- x fp32 [8192][164] -> bf16 [8192][192] (zero pad) -----------------
__global__ void cvt_x(const float* __restrict__ x, unsigned short* __restrict__ xbf) {
    int row = blockIdx.x;
    const float* src = x + (size_t)row * PD_;
    unsigned short* dst = xbf + (size_t)row * 192;
    for (int k = threadIdx.x; k < 192; k += 64)
        dst[k] = f2bf(k < PD_ ? src[k] : 0.f);
}

// --------- weight pretranspose: fp32 [batch][K][N] -> bf16 [batch][N][Kpad] --
__global__ void pretrans(const float* __restrict__ W, unsigned short* __restrict__ out,
                         int K, int N, int Kpad, long sstride, long dstride) {
    int n = blockIdx.x, bb = blockIdx.y;
    const float* src = W + (size_t)bb * sstride;
    unsigned short* dst = out + (size_t)bb * dstride + (size_t)n * Kpad;
    for (int k = threadIdx.x; k < Kpad; k += 64)
        dst[k] = f2bf((k < K && n < N) ? src[(size_t)k * N + n] : 0.f);
}

// --------- init c==15 lanes of packed q/k/v --------------------------------
__global__ void attn_init(const float* __restrict__ mask, unsigned short* __restrict__ qp,
                          unsigned short* __restrict__ kp, unsigned short* __restrict__ vp) {
    int idx = blockIdx.x * blockDim.x + threadIdx.x;   // (b*H+h)*LP + l
    if (idx >= B_ * H_ * LP_) return;
    int l = idx % LP_;
    int b = idx / (H_ * LP_);
    qp[(size_t)idx * 16 + 15] = f2bf(LOG2E_);
    kp[(size_t)idx * 16 + 15] = (mask[b * LP_ + l] != 0.f) ? f2bf(-10000.f) : 0;
    vp[(size_t)idx * 16 + 15] = f2h(1.f);
}

// --------- pack bq|bk|bv per layer into one 720-vector -----------------------
__global__ void pack_bias(const float* __restrict__ bq, const float* __restrict__ bk,
                          const float* __restrict__ bv, float* __restrict__ b720) {
    int i = blockIdx.x;
    for (int n = threadIdx.x; n < 720; n += 256) {
        float v = (n < 240) ? bq[i * 240 + n]
                : (n < 480) ? bk[i * 240 + n - 240]
                            : bv[i * 240 + n - 480];
        b720[i * 720 + n] = v;
    }
}

// ---------------- MFMA GEMM: C = A[M,Kpad]bf16 @ Bt[N,Kpad]bf16 --------------
// tile 128x64, 4 waves (2x2), K-step 32. Staging via global_load_lds.
// flags: 1 relu, 2 accumulate fp32 C, 4 QKV-packed epilogue, 8 bf16 out
__global__ __launch_bounds__(256)
void gemm_mfma(const unsigned short* __restrict__ A,
               const unsigned short* __restrict__ Bt,
               const float* __restrict__ bias,
               float* __restrict__ C, unsigned short* __restrict__ Cbf,
               unsigned short* __restrict__ qp, unsigned short* __restrict__ kp,
               unsigned short* __restrict__ vp,
               int M, int N, int Kpad, int Cstride, int flags)
{
    __shared__ __align__(16) unsigned short As[128 * 32];   // 8 KB
    __shared__ __align__(16) unsigned short Bs[64 * 32];    // 4 KB
    const int tid = threadIdx.x;
    const int bm = blockIdx.x * 128;
    const int bn = blockIdx.y * 64;
    const int wave = tid >> 6, lane = tid & 63;
    const int wm = (wave & 1) * 64, wn = (wave >> 1) * 32;
    const int lq = lane >> 4, lr = lane & 15;

    f32x4 acc[4][2];
    #pragma unroll
    for (int i = 0; i < 4; i++)
        #pragma unroll
        for (int j = 0; j < 2; j++) acc[i][j] = (f32x4){0.f, 0.f, 0.f, 0.f};

    const int srow = lane >> 2;            // 0..15
    const int schk = (lane & 3) << 3;      // 0,8,16,24
    const unsigned short* ga0 = A + (size_t)(bm + wave * 32 + srow) * Kpad + schk;
    const unsigned short* ga1 = A + (size_t)(bm + wave * 32 + 16 + srow) * Kpad + schk;
    const unsigned short* gb  = Bt + (size_t)(bn + wave * 16 + srow) * Kpad + schk;
    char* la0 = (char*)As + wave * 2048;
    char* la1 = (char*)As + wave * 2048 + 1024;
    char* lb  = (char*)Bs + wave * 1024;

    const int nkt = Kpad >> 5;
    for (int kt = 0; kt < nkt; kt++) {
        gl2lds16(ga0, la0);
        gl2lds16(ga1, la1);
        gl2lds16(gb, lb);
        ga0 += 32; ga1 += 32; gb += 32;
        __syncthreads();
        bf16x8 af[4], bfr[2];
        #pragma unroll
        for (int i = 0; i < 4; i++)
            af[i] = *(const bf16x8*)&As[(wm + i * 16 + lr) * 32 + lq * 8];
        #pragma unroll
        for (int j = 0; j < 2; j++)
            bfr[j] = *(const bf16x8*)&Bs[(wn + j * 16 + lr) * 32 + lq * 8];
        #pragma unroll
        for (int i = 0; i < 4; i++)
            #pragma unroll
            for (int j = 0; j < 2; j++)
                acc[i][j] = __builtin_amdgcn_mfma_f32_16x16x32_bf16(af[i], bfr[j], acc[i][j], 0, 0, 0);
        __syncthreads();
    }

    if (flags & 4) {                       // QKV packed epilogue (N=720)
        #pragma unroll
        for (int j = 0; j < 2; j++) {
            int n = bn + wn + j * 16 + lr;
            if (n >= N) continue;
            int which = n / 240;
            int rem = n - which * 240;
            int hh = rem / 15;
            int c = rem - hh * 15;
            unsigned short* dst = (which == 0) ? qp : (which == 1) ? kp : vp;
            float bias_n = bias[n];
            float mult = (which == 0) ? (SCALE_ * LOG2E_) : 1.f;
            #pragma unroll
            for (int i = 0; i < 4; i++)
                #pragma unroll
                for (int r = 0; r < 4; r++) {
                    int m = bm + wm + i * 16 + lq * 4 + r;
                    if (m >= M) continue;
                    float s = (acc[i][j][r] + bias_n) * mult;
                    int b = m / LP_, l = m - b * LP_;
                    unsigned short bits = (which == 2) ? f2h(s) : f2bf(s);
                    dst[(((size_t)b * H_ + hh) * LP_ + l) * 16 + c] = bits;
                }
        }
    } else if (flags & 8) {                // bf16 output
        #pragma unroll
        for (int i = 0; i < 4; i++)
            #pragma unroll
            for (int j = 0; j < 2; j++) {
                int n = bn + wn + j * 16 + lr;
                if (n >= N) continue;
                float bias_n = bias ? bias[n] : 0.f;
                #pragma unroll
                for (int r = 0; r < 4; r++) {
                    int m = bm + wm + i * 16 + lq * 4 + r;
                    if (m >= M) continue;
                    float s = acc[i][j][r] + bias_n;
                    if (flags & 1) s = fmaxf(s, 0.f);
                    Cbf[(size_t)m * Cstride + n] = f2bf(s);
                }
            }
    } else {                               // fp32 output (optionally accumulate)
        #pragma unroll
        for (int i = 0; i < 4; i++)
            #pragma unroll
            for (int j = 0; j < 2; j++) {
                int n = bn + wn + j * 16 + lr;
                if (n >= N) continue;
                float bias_n = bias ? bias[n] : 0.f;
                #pragma unroll
                for (int r = 0; r < 4; r++) {
                    int m = bm + wm + i * 16 + lq * 4 + r;
                    if (m >= M) continue;
                    float s = acc[i][j][r] + bias_n;
                    if (flags & 1) s = fmaxf(s, 0.f);
                    size_t off = (size_t)m * Cstride + n;
                    if (flags & 2) C[off] += s; else C[off] = s;
                }
            }
    }
}

// -------- fused GEMM + residual + LayerNorm ----------------------------------
// C_row = h_row + A@Bt + bias;  h = C_row;  ybf = LN(C_row)*g+b  (bf16)
// tile 64 rows x 240 cols; 4 waves, wave w owns rows [bm+16w, +16).
// Per wave per k-step: 1 A-frag + 15 B-frags, 15 MFMA. Full row per wave
// => LN reduction = in-register j-sum + 4 quad-local shuffles.
__global__ __launch_bounds__(256)
void gemm_ln(const unsigned short* __restrict__ A,
             const unsigned short* __restrict__ Bt,
             const float* __restrict__ bias,
             float* __restrict__ h, unsigned short* __restrict__ ybf,
             const float* __restrict__ g, const float* __restrict__ bb,
             int M, int Kpad, int doLN)
{
    __shared__ __align__(16) unsigned short As[64 * 32];    // 4 KB
    __shared__ __align__(16) unsigned short Bs[256 * 32];   // 16 KB
    const int tid = threadIdx.x;
    const int bm = blockIdx.x * 64;
    const int wave = tid >> 6, lane = tid & 63;
    const int lq = lane >> 4, lr = lane & 15;
    const int srow = lane >> 2;
    const int schk = (lane & 3) << 3;

    f32x4 acc[15];
    #pragma unroll
    for (int j = 0; j < 15; j++) acc[j] = (f32x4){0.f, 0.f, 0.f, 0.f};

    const unsigned short* ga = A + (size_t)(bm + wave * 16 + srow) * Kpad + schk;
    char* la = (char*)As + wave * 1024;
    const unsigned short* gb0 = Bt + (size_t)(wave * 64 + srow) * Kpad + schk;
    const unsigned short* gb1 = gb0 + (size_t)16 * Kpad;
    const unsigned short* gb2 = gb1 + (size_t)16 * Kpad;
    const unsigned short* gb3 = gb2 + (size_t)16 * Kpad;
    char* lb0 = (char*)Bs + wave * 4096;
    char* lb1 = lb0 + 1024;
    char* lb2 = lb1 + 1024;
    char* lb3 = lb2 + 1024;

    const int nkt = Kpad >> 5;
    for (int kt = 0; kt < nkt; kt++) {
        gl2lds16(ga, la);
        gl2lds16(gb0, lb0);
        gl2lds16(gb1, lb1);
        gl2lds16(gb2, lb2);
        gl2lds16(gb3, lb3);
        ga += 32; gb0 += 32; gb1 += 32; gb2 += 32; gb3 += 32;
        __syncthreads();
        bf16x8 af = *(const bf16x8*)&As[(wave * 16 + lr) * 32 + lq * 8];
        #pragma unroll
        for (int j = 0; j < 15; j++) {
            bf16x8 bfr = *(const bf16x8*)&Bs[(j * 16 + lr) * 32 + lq * 8];
            acc[j] = __builtin_amdgcn_mfma_f32_16x16x32_bf16(af, bfr, acc[j], 0, 0, 0);
        }
        __syncthreads();
    }

    // ---- epilogue: bias + residual; update h ----
    const int rb = bm + wave * 16;
    #pragma unroll
    for (int j = 0; j < 15; j++) {
        float bj = bias[j * 16 + lr];
        #pragma unroll
        for (int r = 0; r < 4; r++) {
            int row = rb + lq * 4 + r;
            float v = acc[j][r] + bj;
            if (row < M) {
                float* hp = h + (size_t)row * 240 + j * 16 + lr;
                v += *hp;
                *hp = v;
            }
            acc[j][r] = v;
        }
    }
    if (!doLN) return;
    // ---- LN over each row (full row lives in this wave's quad) ----
    float mean[4], rs[4];
    #pragma unroll
    for (int r = 0; r < 4; r++) {
        float p = 0.f;
        #pragma unroll
        for (int j = 0; j < 15; j++) p += acc[j][r];
        #pragma unroll
        for (int off = 1; off < 16; off <<= 1) p += __shfl_xor(p, off);
        mean[r] = p * (1.f / 240.f);
    }
    #pragma unroll
    for (int r = 0; r < 4; r++) {
        float p = 0.f;
        #pragma unroll
        for (int j = 0; j < 15; j++) {
            float d = acc[j][r] - mean[r];
            p += d * d;
        }
        #pragma unroll
        for (int off = 1; off < 16; off <<= 1) p += __shfl_xor(p, off);
        rs[r] = rsqrtf(p * (1.f / 240.f) + 1e-5f);
    }
    #pragma unroll
    for (int j = 0; j < 15; j++) {
        float gj = g[j * 16 + lr];
        float bj = bb[j * 16 + lr];
        #pragma unroll
        for (int r = 0; r < 4; r++) {
            int row = rb + lq * 4 + r;
            if (row < M)
                ybf[(size_t)row * 256 + j * 16 + lr] =
                    f2bf((acc[j][r] - mean[r]) * rs[r] * gj + bj);
        }
    }
}

// ------------- LN240: wave-per-row, fp32 in -> bf16 out [rows][256] ----------
__global__ __launch_bounds__(256)
void ln240(const float* __restrict__ in, unsigned short* __restrict__ out,
           const float* __restrict__ g, const float* __restrict__ bb) {
    const int row = blockIdx.x * 4 + (threadIdx.x >> 6);
    const int lane = threadIdx.x & 63;
    const float* x = in + (size_t)row * 240;
    float4 v = {0.f, 0.f, 0.f, 0.f};
    if (lane < 60) v = *(const float4*)(x + lane * 4);
    float s = (v.x + v.y) + (v.z + v.w);
    #pragma unroll
    for (int off = 32; off; off >>= 1) s += __shfl_xor(s, off);
    const float mean = s * (1.f / 240.f);
    float4 d;
    d.x = v.x - mean; d.y = v.y - mean; d.z = v.z - mean; d.w = v.w - mean;
    float vs = (lane < 60) ? (d.x * d.x + d.y * d.y) + (d.z * d.z + d.w * d.w) : 0.f;
    #pragma unroll
    for (int off = 32; off; off >>= 1) vs += __shfl_xor(vs, off);
    const float rs = rsqrtf(vs * (1.f / 240.f) + 1e-5f);
    ushort4 o4 = {0, 0, 0, 0};
    if (lane < 60) {
        float4 g4 = *(const float4*)(g + lane * 4);
        float4 b4 = *(const float4*)(bb + lane * 4);
        o4.x = f2bf(d.x * rs * g4.x + b4.x);
        o4.y = f2bf(d.y * rs * g4.y + b4.y);
        o4.z = f2bf(d.z * rs * g4.z + b4.z);
        o4.w = f2bf(d.w * rs * g4.w + b4.w);
    }
    *(ushort4*)(out + (size_t)row * 256 + lane * 4) = o4;   // lanes 60..63: pad zeros
}

// ------------- LN480+relu: wave-per-row, fp32 in -> bf16 out [rows][480] -----
__global__ __launch_bounds__(256)
void ln480(const float* __restrict__ in, unsigned short* __restrict__ out,
           const float* __restrict__ g, const float* __restrict__ bb) {
    const int row = blockIdx.x * 4 + (threadIdx.x >> 6);
    const int lane = threadIdx.x & 63;
    const float* x = in + (size_t)row * 480;
    float4 va = {0.f,0.f,0.f,0.f}, vb = {0.f,0.f,0.f,0.f};
    if (lane < 60) {
        va = *(const float4*)(x + lane * 8);
        vb = *(const float4*)(x + lane * 8 + 4);
    }
    float s = ((va.x + va.y) + (va.z + va.w)) + ((vb.x + vb.y) + (vb.z + vb.w));
    #pragma unroll
    for (int off = 32; off; off >>= 1) s += __shfl_xor(s, off);
    const float mean = s * (1.f / 480.f);
    float4 da, db;
    da.x = va.x - mean; da.y = va.y - mean; da.z = va.z - mean; da.w = va.w - mean;
    db.x = vb.x - mean; db.y = vb.y - mean; db.z = vb.z - mean; db.w = vb.w - mean;
    float vs = (lane < 60) ? ((da.x*da.x + da.y*da.y) + (da.z*da.z + da.w*da.w)) +
                             ((db.x*db.x + db.y*db.y) + (db.z*db.z + db.w*db.w)) : 0.f;
    #pragma unroll
    for (int off = 32; off; off >>= 1) vs += __shfl_xor(vs, off);
    const float rs = rsqrtf(vs * (1.f / 480.f) + 1e-5f);
    if (lane < 60) {
        float4 ga = *(const float4*)(g + lane * 8);
        float4 gb = *(const float4*)(g + lane * 8 + 4);
        float4 ba = *(const float4*)(bb + lane * 8);
        float4 b2 = *(const float4*)(bb + lane * 8 + 4);
        ushort4 oa, ob;
        oa.x = f2bf(fmaxf(da.x * rs * ga.x + ba.x, 0.f));
        oa.y = f2bf(fmaxf(da.y * rs * ga.y + ba.y, 0.f));
        oa.z = f2bf(fmaxf(da.z * rs * ga.z + ba.z, 0.f));
        oa.w = f2bf(fmaxf(da.w * rs * ga.w + ba.w, 0.f));
        ob.x = f2bf(fmaxf(db.x * rs * gb.x + b2.x, 0.f));
        ob.y = f2bf(fmaxf(db.y * rs * gb.y + b2.y, 0.f));
        ob.z = f2bf(fmaxf(db.z * rs * gb.z + b2.z, 0.f));
        ob.w = f2bf(fmaxf(db.w * rs * gb.w + b2.w, 0.f));
        *(ushort4*)(out + (size_t)row * 480 + lane * 8) = oa;
        *(ushort4*)(out + (size_t)row * 480 + lane * 8 + 4) = ob;
    }
}

// -------- embed finish: LN(g2)+relu+pos for tokens, cls row for l==0 ---------
__global__ void embed_finish(const float* __restrict__ tmp,
                             const float* __restrict__ g, const float* __restrict__ bb,
                             const float* __restrict__ pos, const float* __restrict__ cls,
                             float* __restrict__ h) {
    int row = blockIdx.x;
    int b = row / LP_, l = row % LP_;
    int t = threadIdx.x;
    float* out = h + (size_t)row * D_;
    if (l == 0) {
        if (t < D_) out[t] = cls[t];
        return;
    }
    const float* x = tmp + ((size_t)b * L_ + (l - 1)) * D_;
    float v0 = (t < D_) ? x[t] : 0.f;
    __shared__ float red[256];
    red[t] = v0;
    __syncthreads();
    for (int off = 128; off > 0; off >>= 1) {
        if (t < off) red[t] += red[t + off];
        __syncthreads();
    }
    float mean = red[0] / D_;
    __syncthreads();
    float d0 = (t < D_) ? v0 - mean : 0.f;
    red[t] = d0 * d0;
    __syncthreads();
    for (int off = 128; off > 0; off >>= 1) {
        if (t < off) red[t] += red[t + off];
        __syncthreads();
    }
    float rs = rsqrtf(red[0] / D_ + 1e-5f);
    if (t < D_) {
        float r = d0 * rs * g[t] + bb[t];
        out[t] = fmaxf(r, 0.f) + pos[(size_t)(l - 1) * D_ + t];
    }
}

// ---------------- MFMA flash attention: block per (b,h), 4 waves -------------
__global__ __launch_bounds__(256)
void attn_mfma(const unsigned short* __restrict__ qp, const unsigned short* __restrict__ kp,
               const unsigned short* __restrict__ vp, unsigned short* __restrict__ obf)
{
    __shared__ __align__(16) unsigned short Kl[KP_ * 24];    // 13.5 KB
    __shared__ __align__(16) unsigned short Vt[16 * 296];    // 9.25 KB  V^T f16
    __shared__ __align__(16) unsigned short Pl[4][16 * 296]; // 37 KB    P f16 per wave
    const int hh = blockIdx.x, b = blockIdx.y;
    const int tid = threadIdx.x;
    const int wave = tid >> 6, lane = tid & 63;
    const int lq = lane >> 4, lr = lane & 15;
    const size_t base = ((size_t)b * H_ + hh) * LP_ * 16;

    for (int key = tid; key < KP_; key += 256) {
        uint4 z = {0u, 0u, 0u, 0u};
        uint4 k0 = z, k1 = z, v0 = z, v1 = z;
        if (key < LP_) {
            k0 = *(const uint4*)(kp + base + (size_t)key * 16);
            k1 = *(const uint4*)(kp + base + (size_t)key * 16 + 8);
            v0 = *(const uint4*)(vp + base + (size_t)key * 16);
            v1 = *(const uint4*)(vp + base + (size_t)key * 16 + 8);
        } else {
            k1.w = 0xC61C0000u;            // elem15 = bf16(-10000) sentinel
        }
        *(uint4*)&Kl[key * 24] = k0;
        *(uint4*)&Kl[key * 24 + 8] = k1;
        unsigned short vs[8];
        *(uint4*)vs = v0;
        #pragma unroll
        for (int d = 0; d < 8; d++) Vt[d * 296 + key] = vs[d];
        *(uint4*)vs = v1;
        #pragma unroll
        for (int d = 0; d < 8; d++) Vt[(d + 8) * 296 + key] = vs[d];
    }
    __syncthreads();

    unsigned short* Pw = &Pl[wave][0];
    for (int qt = wave; qt < 17; qt += 4) {
        const int qrow = qt * 16 + lr;
        bf16x8 aq = {0, 0, 0, 0, 0, 0, 0, 0};
        if (lq < 2)
            aq = *(const bf16x8*)(qp + base + (size_t)qrow * 16 + lq * 8);
        for (int kt = 0; kt < 18; kt++) {
            bf16x8 bk = {0, 0, 0, 0, 0, 0, 0, 0};
            if (lq < 2)
                bk = *(const bf16x8*)&Kl[(kt * 16 + lr) * 24 + lq * 8];
            f32x4 sacc = {0.f, 0.f, 0.f, 0.f};
            sacc = __builtin_amdgcn_mfma_f32_16x16x32_bf16(aq, bk, sacc, 0, 0, 0);
            #pragma unroll
            for (int r = 0; r < 4; r++)
                Pw[(lq * 4 + r) * 296 + kt * 16 + lr] = f2h(exp2f(sacc[r]));
        }
        asm volatile("s_waitcnt lgkmcnt(0)" ::: "memory");
        f32x4 o = {0.f, 0.f, 0.f, 0.f};
        #pragma unroll
        for (int ks = 0; ks < 9; ks++) {
            f16x8 ap = *(const f16x8*)&Pw[lr * 296 + ks * 32 + lq * 8];
            f16x8 bv = *(const f16x8*)&Vt[lr * 296 + ks * 32 + lq * 8];
            o = __builtin_amdgcn_mfma_f32_16x16x32_f16(ap, bv, o, 0, 0, 0);
        }
        asm volatile("s_waitcnt lgkmcnt(0)" ::: "memory");
        #pragma unroll
        for (int r = 0; r < 4; r++) {
            float denom = __shfl(o[r], lane | 15);
            int q = qt * 16 + lq * 4 + r;
            if (q < LP_ && lr < 15)
                obf[((size_t)b * LP_ + q) * 256 + hh * DK_ + lr] = f2bf(o[r] / denom);
        }
    }
    // zero pad cols 240..255 (once per row, by hh==0 block)
    if (hh == 0) {
        for (int q = tid; q < LP_; q += 256) {
            uint4 z = {0u, 0u, 0u, 0u};
            *(uint4*)(obf + ((size_t)b * LP_ + q) * 256 + 240) = z;
            *(uint4*)(obf + ((size_t)b * LP_ + q) * 256 + 248) = z;
        }
    }
}

// ---------------- masked mean pool (2-stage) ---------------------------------
__global__ void pool_partial(const float* __restrict__ h, const float* __restrict__ mask,
                             float* __restrict__ partial) {
    int b = blockIdx.x, slice = blockIdx.y;
    int d = threadIdx.x;
    if (d >= D_) return;
    float s = 0.f;
    int l0 = slice * 29;
    for (int i = 0; i < 29; i++) {
        int l = l0 + i;
        if (l < LP_ && mask[b * LP_ + l] == 0.f)
            s += h[((size_t)b * LP_ + l) * D_ + d];
    }
    partial[((size_t)b * 9 + slice) * D_ + d] = s;
}

__global__ void pool_final(const float* __restrict__ partial, const float* __restrict__ mask,
                           float* __restrict__ pool) {
    int b = blockIdx.x;
    int t = threadIdx.x;
    __shared__ float red[256];
    float c = 0.f;
    for (int l = t; l < LP_; l += 256) c += (mask[b * LP_ + l] == 0.f) ? 1.f : 0.f;
    red[t] = c;
    __syncthreads();
    for (int off = 128; off > 0; off >>= 1) {
        if (t < off) red[t] += red[t + off];
        __syncthreads();
    }
    float inv = 1.f / red[0];
    if (t < D_) {
        float s = 0.f;
        #pragma unroll
        for (int sl = 0; sl < 9; sl++) s += partial[((size_t)b * 9 + sl) * D_ + t];
        pool[b * D_ + t] = s * inv;
    }
}

// ---------------- logits -----------------------------------------------------
__global__ void logits_kernel(const float* __restrict__ pool, const float* __restrict__ W,
                              const float* __restrict__ bias, float* __restrict__ out) {
    int idx = blockIdx.x * blockDim.x + threadIdx.x;
    if (idx >= B_ * NC_) return;
    int b = idx / NC_, n = idx - b * NC_;
    float s = bias[n];
    const float* p = pool + b * D_;
    for (int kk = 0; kk < D_; kk++) s += p[kk] * W[(size_t)kk * NC_ + n];
    out[idx] = s;
}

extern "C" void kernel_launch(void* const* d_in, const int* in_sizes, int n_in,
                              void* d_out, int out_size, void* d_ws, size_t ws_size,
                              hipStream_t stream) {
    const float* x        = (const float*)d_in[0];
    const float* pos      = (const float*)d_in[1];
    const float* cls      = (const float*)d_in[2];
    const float* e_W1     = (const float*)d_in[3];
    const float* e_b1     = (const float*)d_in[4];
    const float* e_g1     = (const float*)d_in[5];
    const float* e_bn1    = (const float*)d_in[6];
    const float* e_W2     = (const float*)d_in[7];
    const float* e_b2     = (const float*)d_in[8];
    const float* e_g2     = (const float*)d_in[9];
    const float* e_bn2    = (const float*)d_in[10];
    const float* ln1_g    = (const float*)d_in[11];
    const float* ln1_b    = (const float*)d_in[12];
    const float* Wq       = (const float*)d_in[13];
    const float* bq       = (const float*)d_in[14];
    const float* Wk       = (const float*)d_in[15];
    const float* bk       = (const float*)d_in[16];
    const float* Wv       = (const float*)d_in[17];
    const float* bv       = (const float*)d_in[18];
    const float* Wo       = (const float*)d_in[19];
    const float* bo       = (const float*)d_in[20];
    const float* ln2_g    = (const float*)d_in[21];
    const float* ln2_b    = (const float*)d_in[22];
    const float* W1       = (const float*)d_in[23];
    const float* b1       = (const float*)d_in[24];
    const float* W2       = (const float*)d_in[25];
    const float* b2       = (const float*)d_in[26];
    const float* logit_W  = (const float*)d_in[27];
    const float* logit_b  = (const float*)d_in[28];
    float* out = (float*)d_out;

    const size_t TOK  = (size_t)B_ * LP_;            // 8224
    const size_t TOKP = 8320;                        // padded to 65*128
    const size_t HN   = TOK * D_;
    const size_t QN   = (size_t)B_ * H_ * LP_ * 16;  // 2,105,344

    char* wsb = (char*)d_ws;
    size_t cur = 0;
    auto take = [&](size_t bytes) { void* p = wsb + cur; cur += (bytes + 15) & ~15ULL; return p; };
    float* mask = (float*)take(8224 * 4);
    float* h    = (float*)take(HN * 4);
    float* b720 = (float*)take(NB_ * 720 * 4);
    float* pl   = (float*)take(B_ * D_ * 4);
    float* part = (float*)take((size_t)B_ * 9 * D_ * 4);
    void* regionA = take((size_t)8192 * 480 * 4);
    float* tmp1 = (float*)regionA;
    unsigned short* tbf = (unsigned short*)regionA;
    void* regionB = take(TOKP * 256 * 2 * 2);
    float* y32 = (float*)regionB;
    unsigned short* ybf = (unsigned short*)regionB;
    unsigned short* obf = ybf + TOKP * 256;
    unsigned short* xbf  = (unsigned short*)take((size_t)8192 * 192 * 2);
    unsigned short* We1  = (unsigned short*)take((size_t)512 * 192 * 2);
    unsigned short* We2  = (unsigned short*)take((size_t)256 * 480 * 2);
    unsigned short* Wqkv = (unsigned short*)take((size_t)NB_ * 768 * 256 * 2);
    unsigned short* WoT  = (unsigned short*)take((size_t)NB_ * 256 * 256 * 2);
    unsigned short* W1T  = (unsigned short*)take((size_t)NB_ * 512 * 256 * 2);
    unsigned short* W2T  = (unsigned short*)take((size_t)NB_ * 256 * 480 * 2);
    unsigned short* qp = (unsigned short*)take(QN * 3 * 2 + 16 * 16 * 2);
    unsigned short* kp = qp + QN;
    unsigned short* vp = kp + QN;
    unsigned short* t480bf = qp;   // aliases qp/kp, dead before attn_init

    const int BS = 256;
    auto blocks = [](size_t n) { return (int)((n + 255) / 256); };

    // prep
    mask_kernel<<<blocks(TOK), BS, 0, stream>>>(x, mask);
    pack_bias<<<NB_, BS, 0, stream>>>(bq, bk, bv, b720);
    cvt_x<<<8192, 64, 0, stream>>>(x, xbf);
    pretrans<<<dim3(480, 1), 64, 0, stream>>>(e_W1, We1, PD_, 480, 192, 0, 0);
    pretrans<<<dim3(240, 1), 64, 0, stream>>>(e_W2, We2, 480, 240, 480, 0, 0);
    pretrans<<<dim3(240, NB_), 64, 0, stream>>>(Wq, Wqkv,           240, 240, 256, 240*240, 768*256);
    pretrans<<<dim3(240, NB_), 64, 0, stream>>>(Wk, Wqkv + 240*256, 240, 240, 256, 240*240, 768*256);
    pretrans<<<dim3(240, NB_), 64, 0, stream>>>(Wv, Wqkv + 480*256, 240, 240, 256, 240*240, 768*256);
    pretrans<<<dim3(256, NB_), 64, 0, stream>>>(Wo, WoT,            240, 240, 256, 240*240, 256*256);
    pretrans<<<dim3(480, NB_), 64, 0, stream>>>(W1, W1T,            240, 480, 256, 240*480, 512*256);
    pretrans<<<dim3(256, NB_), 64, 0, stream>>>(W2, W2T,            480, 240, 480, 480*240, 256*480);

    // embed
    gemm_mfma<<<dim3(64, 8), BS, 0, stream>>>(xbf, We1, e_b1, tmp1, nullptr,
                                              nullptr, nullptr, nullptr,
                                              8192, 480, 192, 480, 0);
    ln480<<<2048, BS, 0, stream>>>(tmp1, t480bf, e_g1, e_bn1);
    gemm_mfma<<<dim3(64, 4), BS, 0, stream>>>(t480bf, We2, e_b2, y32, nullptr,
                                              nullptr, nullptr, nullptr,
                                              8192, 240, 480, 240, 0);
    embed_finish<<<(int)TOK, BS, 0, stream>>>(y32, e_g2, e_bn2, pos, cls, h);
    attn_init<<<blocks((size_t)B_ * H_ * LP_), BS, 0, stream>>>(mask, qp, kp, vp);
    // layer-0 ln1 (later layers' ln1 are fused into the previous W2 gemm_ln)
    ln240<<<(int)(TOK / 4), BS, 0, stream>>>(h, ybf, ln1_g, ln1_b);

    for (int i = 0; i < NB_; i++) {
        gemm_mfma<<<dim3(65, 12), BS, 0, stream>>>(ybf, Wqkv + (size_t)i * 768 * 256,
                                                   b720 + i * 720, nullptr, nullptr,
                                                   qp, kp, vp,
                                                   (int)TOK, 720, 256, 0, 4);
        attn_mfma<<<dim3(H_, B_), BS, 0, stream>>>(qp, kp, vp, obf);
        // Wo GEMM + residual + ln2 -> ybf
        gemm_ln<<<130, BS, 0, stream>>>(obf, WoT + (size_t)i * 256 * 256, bo + i * D_,
                                        h, ybf, ln2_g + i * D_, ln2_b + i * D_,
                                        (int)TOK, 256, 1);
        gemm_mfma<<<dim3(65, 8), BS, 0, stream>>>(ybf, W1T + (size_t)i * 512 * 256,
                                                  b1 + i * HID_, nullptr, tbf,
                                                  nullptr, nullptr, nullptr,
                                                  (int)TOK, 480, 256, 480, 1 | 8);
        // W2 GEMM + residual + next layer's ln1 -> ybf (last layer: no LN)
        const float* ng = (i < NB_ - 1) ? ln1_g + (i + 1) * D_ : ln1_g;
        const float* nb = (i < NB_ - 1) ? ln1_b + (i + 1) * D_ : ln1_b;
        gemm_ln<<<130, BS, 0, stream>>>(tbf, W2T + (size_t)i * 256 * 480, b2 + i * D_,
                                        h, ybf, ng, nb,
                                        (int)TOK, 480, (i < NB_ - 1) ? 1 : 0);
    }

    pool_partial<<<dim3(B_, 9), BS, 0, stream>>>(h, mask, part);
    pool_final<<<B_, BS, 0, stream>>>(part, mask, pl);
    logits_kernel<<<blocks((size_t)B_ * NC_), BS, 0, stream>>>(pl, logit_W, logit_b, out);
}

// Round 11
// 911.122 us; speedup vs baseline: 1.2473x; 1.1513x over previous
//
#include <hip/hip_runtime.h>
#include <math.h>

#define B_  32
#define L_  256
#define PD_ 164
#define D_  240
#define H_  16
#define NB_ 6
#define NC_ 250
#define DK_ 15
#define HID_ 480
#define LP_ 257
#define KP_ 288            // keys padded to 9*32
#define SCALE_ 0.2581988897471611f   // 1/sqrt(15)
#define LOG2E_ 1.4426950408889634f

typedef __attribute__((ext_vector_type(8))) short bf16x8;
typedef __attribute__((ext_vector_type(8))) _Float16 f16x8;
typedef __attribute__((ext_vector_type(4))) float f32x4;

static __device__ inline unsigned short f2bf(float x) {
    unsigned u = __builtin_bit_cast(unsigned, x);
    u += 0x7FFFu + ((u >> 16) & 1u);     // RNE (finite values only)
    return (unsigned short)(u >> 16);
}
static __device__ inline unsigned short f2h(float x) {
    _Float16 h = (_Float16)x;
    return __builtin_bit_cast(unsigned short, h);
}

// async global->LDS, 16B per lane; lds dest must be wave-uniform base (+lane*16)
static __device__ inline void gl2lds16(const void* g, void* l) {
    __builtin_amdgcn_global_load_lds(
        (const __attribute__((address_space(1))) unsigned int*)g,
        (__attribute__((address_space(3))) unsigned int*)l, 16, 0, 0);
}

// ---------------- mask ----------------
__global__ void mask_kernel(const float* __restrict__ x, float* __restrict__ mask) {
    int idx = blockIdx.x * blockDim.x + threadIdx.x;
    if (idx >= B_ * LP_) return;
    int b = idx / LP_, l = idx % LP_;
    if (l == 0) { mask[idx] = 0.f; return; }
    const float* xr = x + ((size_t)b * L_ + (l - 1)) * PD_;
    float mx = -1e30f;
    for (int j = 0; j < PD_; j++) mx = fmaxf(mx, xr[j]);
    mask[idx] = (mx == 0.f) ? 1.f : 0.f;
}

// --------- x fp32 [8192][164] -> bf16 [8192][192] (zero pad) -----------------
__global__ void cvt_x(const float* __restrict__ x, unsigned short* __restrict__ xbf) {
    int row = blockIdx.x;
    const float* src = x + (size_t)row * PD_;
    unsigned short* dst = xbf + (size_t)row * 192;
    for (int k = threadIdx.x; k < 192; k += 64)
        dst[k] = f2bf(k < PD_ ? src[k] : 0.f);
}

// --------- weight pretranspose: fp32 [batch][K][N] -> bf16 [batch][N][Kpad] --
__global__ void pretrans(const float* __restrict__ W, unsigned short* __restrict__ out,
                         int K, int N, int Kpad, long sstride, long dstride) {
    int n = blockIdx.x, bb = blockIdx.y;
    const float* src = W + (size_t)bb * sstride;
    unsigned short* dst = out + (size_t)bb * dstride + (size_t)n * Kpad;
    for (int k = threadIdx.x; k < Kpad; k += 64)
        dst[k] = f2bf((k < K && n < N) ? src[(size_t)k * N + n] : 0.f);
}

// --------- init c==15 lanes of packed q/k/v --------------------------------
__global__ void attn_init(const float* __restrict__ mask, unsigned short* __restrict__ qp,
                          unsigned short* __restrict__ kp, unsigned short* __restrict__ vp) {
    int idx = blockIdx.x * blockDim.x + threadIdx.x;   // (b*H+h)*LP + l
    if (idx >= B_ * H_ * LP_) return;
    int l = idx % LP_;
    int b = idx / (H_ * LP_);
    qp[(size_t)idx * 16 + 15] = f2bf(LOG2E_);
    kp[(size_t)idx * 16 + 15] = (mask[b * LP_ + l] != 0.f) ? f2bf(-10000.f) : 0;
    vp[(size_t)idx * 16 + 15] = f2h(1.f);
}

// --------- pack bq|bk|bv per layer into one 720-vector -----------------------
__global__ void pack_bias(const float* __restrict__ bq, const float* __restrict__ bk,
                          const float* __restrict__ bv, float* __restrict__ b720) {
    int i = blockIdx.x;
    for (int n = threadIdx.x; n < 720; n += 256) {
        float v = (n < 240) ? bq[i * 240 + n]
                : (n < 480) ? bk[i * 240 + n - 240]
                            : bv[i * 240 + n - 480];
        b720[i * 720 + n] = v;
    }
}

// ---------------- MFMA GEMM: C = A[M,Kpad]bf16 @ Bt[N,Kpad]bf16 --------------
// tile 128x64, 4 waves (2x2), K-step 32. Staging via global_load_lds.
// Optional K-split via gridDim.z: each z-block does a slice of the K loop and
// (flags&2 path) atomically accumulates its partial into C. Bias added by z==0.
// flags: 1 relu, 2 accumulate fp32 C, 4 QKV-packed epilogue, 8 bf16 out
__global__ __launch_bounds__(256)
void gemm_mfma(const unsigned short* __restrict__ A,
               const unsigned short* __restrict__ Bt,
               const float* __restrict__ bias,
               float* __restrict__ C, unsigned short* __restrict__ Cbf,
               unsigned short* __restrict__ qp, unsigned short* __restrict__ kp,
               unsigned short* __restrict__ vp,
               int M, int N, int Kpad, int Cstride, int flags)
{
    __shared__ __align__(16) unsigned short As[128 * 32];   // 8 KB
    __shared__ __align__(16) unsigned short Bs[64 * 32];    // 4 KB
    const int tid = threadIdx.x;
    const int bm = blockIdx.x * 128;
    const int bn = blockIdx.y * 64;
    const int zs = gridDim.z, zi = blockIdx.z;
    const int wave = tid >> 6, lane = tid & 63;
    const int wm = (wave & 1) * 64, wn = (wave >> 1) * 32;
    const int lq = lane >> 4, lr = lane & 15;

    f32x4 acc[4][2];
    #pragma unroll
    for (int i = 0; i < 4; i++)
        #pragma unroll
        for (int j = 0; j < 2; j++) acc[i][j] = (f32x4){0.f, 0.f, 0.f, 0.f};

    const int srow = lane >> 2;            // 0..15
    const int schk = (lane & 3) << 3;      // 0,8,16,24
    const int nkt = Kpad >> 5;
    const int kt0 = (nkt * zi) / zs;
    const int kt1 = (nkt * (zi + 1)) / zs;

    const unsigned short* ga0 = A + (size_t)(bm + wave * 32 + srow) * Kpad + schk + kt0 * 32;
    const unsigned short* ga1 = A + (size_t)(bm + wave * 32 + 16 + srow) * Kpad + schk + kt0 * 32;
    const unsigned short* gb  = Bt + (size_t)(bn + wave * 16 + srow) * Kpad + schk + kt0 * 32;
    char* la0 = (char*)As + wave * 2048;
    char* la1 = (char*)As + wave * 2048 + 1024;
    char* lb  = (char*)Bs + wave * 1024;

    for (int kt = kt0; kt < kt1; kt++) {
        gl2lds16(ga0, la0);
        gl2lds16(ga1, la1);
        gl2lds16(gb, lb);
        ga0 += 32; ga1 += 32; gb += 32;
        __syncthreads();
        bf16x8 af[4], bfr[2];
        #pragma unroll
        for (int i = 0; i < 4; i++)
            af[i] = *(const bf16x8*)&As[(wm + i * 16 + lr) * 32 + lq * 8];
        #pragma unroll
        for (int j = 0; j < 2; j++)
            bfr[j] = *(const bf16x8*)&Bs[(wn + j * 16 + lr) * 32 + lq * 8];
        #pragma unroll
        for (int i = 0; i < 4; i++)
            #pragma unroll
            for (int j = 0; j < 2; j++)
                acc[i][j] = __builtin_amdgcn_mfma_f32_16x16x32_bf16(af[i], bfr[j], acc[i][j], 0, 0, 0);
        __syncthreads();
    }

    if (flags & 4) {                       // QKV packed epilogue (N=720)
        #pragma unroll
        for (int j = 0; j < 2; j++) {
            int n = bn + wn + j * 16 + lr;
            if (n >= N) continue;
            int which = n / 240;
            int rem = n - which * 240;
            int hh = rem / 15;
            int c = rem - hh * 15;
            unsigned short* dst = (which == 0) ? qp : (which == 1) ? kp : vp;
            float bias_n = bias[n];
            float mult = (which == 0) ? (SCALE_ * LOG2E_) : 1.f;
            #pragma unroll
            for (int i = 0; i < 4; i++)
                #pragma unroll
                for (int r = 0; r < 4; r++) {
                    int m = bm + wm + i * 16 + lq * 4 + r;
                    if (m >= M) continue;
                    float s = (acc[i][j][r] + bias_n) * mult;
                    int b = m / LP_, l = m - b * LP_;
                    unsigned short bits = (which == 2) ? f2h(s) : f2bf(s);
                    dst[(((size_t)b * H_ + hh) * LP_ + l) * 16 + c] = bits;
                }
        }
    } else if (flags & 8) {                // bf16 output
        #pragma unroll
        for (int i = 0; i < 4; i++)
            #pragma unroll
            for (int j = 0; j < 2; j++) {
                int n = bn + wn + j * 16 + lr;
                if (n >= N) continue;
                float bias_n = bias ? bias[n] : 0.f;
                #pragma unroll
                for (int r = 0; r < 4; r++) {
                    int m = bm + wm + i * 16 + lq * 4 + r;
                    if (m >= M) continue;
                    float s = acc[i][j][r] + bias_n;
                    if (flags & 1) s = fmaxf(s, 0.f);
                    Cbf[(size_t)m * Cstride + n] = f2bf(s);
                }
            }
    } else {                               // fp32 output (optionally accumulate)
        #pragma unroll
        for (int i = 0; i < 4; i++)
            #pragma unroll
            for (int j = 0; j < 2; j++) {
                int n = bn + wn + j * 16 + lr;
                if (n >= N) continue;
                float bias_n = (bias && zi == 0) ? bias[n] : 0.f;
                #pragma unroll
                for (int r = 0; r < 4; r++) {
                    int m = bm + wm + i * 16 + lq * 4 + r;
                    if (m >= M) continue;
                    float s = acc[i][j][r] + bias_n;
                    if (flags & 1) s = fmaxf(s, 0.f);
                    size_t off = (size_t)m * Cstride + n;
                    if (flags & 2) {
                        if (zs > 1) atomicAdd(&C[off], s);
                        else C[off] += s;
                    } else C[off] = s;
                }
            }
    }
}

// ------------- LN240: wave-per-row, fp32 in -> bf16 out [rows][256] ----------
__global__ __launch_bounds__(256)
void ln240(const float* __restrict__ in, unsigned short* __restrict__ out,
           const float* __restrict__ g, const float* __restrict__ bb) {
    const int row = blockIdx.x * 4 + (threadIdx.x >> 6);
    const int lane = threadIdx.x & 63;
    const float* x = in + (size_t)row * 240;
    float4 v = {0.f, 0.f, 0.f, 0.f};
    if (lane < 60) v = *(const float4*)(x + lane * 4);
    float s = (v.x + v.y) + (v.z + v.w);
    #pragma unroll
    for (int off = 32; off; off >>= 1) s += __shfl_xor(s, off);
    const float mean = s * (1.f / 240.f);
    float4 d;
    d.x = v.x - mean; d.y = v.y - mean; d.z = v.z - mean; d.w = v.w - mean;
    float vs = (lane < 60) ? (d.x * d.x + d.y * d.y) + (d.z * d.z + d.w * d.w) : 0.f;
    #pragma unroll
    for (int off = 32; off; off >>= 1) vs += __shfl_xor(vs, off);
    const float rs = rsqrtf(vs * (1.f / 240.f) + 1e-5f);
    ushort4 o4 = {0, 0, 0, 0};
    if (lane < 60) {
        float4 g4 = *(const float4*)(g + lane * 4);
        float4 b4 = *(const float4*)(bb + lane * 4);
        o4.x = f2bf(d.x * rs * g4.x + b4.x);
        o4.y = f2bf(d.y * rs * g4.y + b4.y);
        o4.z = f2bf(d.z * rs * g4.z + b4.z);
        o4.w = f2bf(d.w * rs * g4.w + b4.w);
    }
    *(ushort4*)(out + (size_t)row * 256 + lane * 4) = o4;   // lanes 60..63: pad zeros
}

// ------------- LN480+relu: wave-per-row, fp32 in -> bf16 out [rows][480] -----
__global__ __launch_bounds__(256)
void ln480(const float* __restrict__ in, unsigned short* __restrict__ out,
           const float* __restrict__ g, const float* __restrict__ bb) {
    const int row = blockIdx.x * 4 + (threadIdx.x >> 6);
    const int lane = threadIdx.x & 63;
    const float* x = in + (size_t)row * 480;
    float4 va = {0.f,0.f,0.f,0.f}, vb = {0.f,0.f,0.f,0.f};
    if (lane < 60) {
        va = *(const float4*)(x + lane * 8);
        vb = *(const float4*)(x + lane * 8 + 4);
    }
    float s = ((va.x + va.y) + (va.z + va.w)) + ((vb.x + vb.y) + (vb.z + vb.w));
    #pragma unroll
    for (int off = 32; off; off >>= 1) s += __shfl_xor(s, off);
    const float mean = s * (1.f / 480.f);
    float4 da, db;
    da.x = va.x - mean; da.y = va.y - mean; da.z = va.z - mean; da.w = va.w - mean;
    db.x = vb.x - mean; db.y = vb.y - mean; db.z = vb.z - mean; db.w = vb.w - mean;
    float vs = (lane < 60) ? ((da.x*da.x + da.y*da.y) + (da.z*da.z + da.w*da.w)) +
                             ((db.x*db.x + db.y*db.y) + (db.z*db.z + db.w*db.w)) : 0.f;
    #pragma unroll
    for (int off = 32; off; off >>= 1) vs += __shfl_xor(vs, off);
    const float rs = rsqrtf(vs * (1.f / 480.f) + 1e-5f);
    if (lane < 60) {
        float4 ga = *(const float4*)(g + lane * 8);
        float4 gb = *(const float4*)(g + lane * 8 + 4);
        float4 ba = *(const float4*)(bb + lane * 8);
        float4 b2 = *(const float4*)(bb + lane * 8 + 4);
        ushort4 oa, ob;
        oa.x = f2bf(fmaxf(da.x * rs * ga.x + ba.x, 0.f));
        oa.y = f2bf(fmaxf(da.y * rs * ga.y + ba.y, 0.f));
        oa.z = f2bf(fmaxf(da.z * rs * ga.z + ba.z, 0.f));
        oa.w = f2bf(fmaxf(da.w * rs * ga.w + ba.w, 0.f));
        ob.x = f2bf(fmaxf(db.x * rs * gb.x + b2.x, 0.f));
        ob.y = f2bf(fmaxf(db.y * rs * gb.y + b2.y, 0.f));
        ob.z = f2bf(fmaxf(db.z * rs * gb.z + b2.z, 0.f));
        ob.w = f2bf(fmaxf(db.w * rs * gb.w + b2.w, 0.f));
        *(ushort4*)(out + (size_t)row * 480 + lane * 8) = oa;
        *(ushort4*)(out + (size_t)row * 480 + lane * 8 + 4) = ob;
    }
}

// -------- embed finish: LN(g2)+relu+pos for tokens, cls row for l==0 ---------
__global__ void embed_finish(const float* __restrict__ tmp,
                             const float* __restrict__ g, const float* __restrict__ bb,
                             const float* __restrict__ pos, const float* __restrict__ cls,
                             float* __restrict__ h) {
    int row = blockIdx.x;
    int b = row / LP_, l = row % LP_;
    int t = threadIdx.x;
    float* out = h + (size_t)row * D_;
    if (l == 0) {
        if (t < D_) out[t] = cls[t];
        return;
    }
    const float* x = tmp + ((size_t)b * L_ + (l - 1)) * D_;
    float v0 = (t < D_) ? x[t] : 0.f;
    __shared__ float red[256];
    red[t] = v0;
    __syncthreads();
    for (int off = 128; off > 0; off >>= 1) {
        if (t < off) red[t] += red[t + off];
        __syncthreads();
    }
    float mean = red[0] / D_;
    __syncthreads();
    float d0 = (t < D_) ? v0 - mean : 0.f;
    red[t] = d0 * d0;
    __syncthreads();
    for (int off = 128; off > 0; off >>= 1) {
        if (t < off) red[t] += red[t + off];
        __syncthreads();
    }
    float rs = rsqrtf(red[0] / D_ + 1e-5f);
    if (t < D_) {
        float r = d0 * rs * g[t] + bb[t];
        out[t] = fmaxf(r, 0.f) + pos[(size_t)(l - 1) * D_ + t];
    }
}

// ---------------- MFMA flash attention: block per (b,h), 4 waves -------------
__global__ __launch_bounds__(256)
void attn_mfma(const unsigned short* __restrict__ qp, const unsigned short* __restrict__ kp,
               const unsigned short* __restrict__ vp, unsigned short* __restrict__ obf)
{
    __shared__ __align__(16) unsigned short Kl[KP_ * 24];    // 13.5 KB
    __shared__ __align__(16) unsigned short Vt[16 * 296];    // 9.25 KB  V^T f16
    __shared__ __align__(16) unsigned short Pl[4][16 * 296]; // 37 KB    P f16 per wave
    const int hh = blockIdx.x, b = blockIdx.y;
    const int tid = threadIdx.x;
    const int wave = tid >> 6, lane = tid & 63;
    const int lq = lane >> 4, lr = lane & 15;
    const size_t base = ((size_t)b * H_ + hh) * LP_ * 16;

    for (int key = tid; key < KP_; key += 256) {
        uint4 z = {0u, 0u, 0u, 0u};
        uint4 k0 = z, k1 = z, v0 = z, v1 = z;
        if (key < LP_) {
            k0 = *(const uint4*)(kp + base + (size_t)key * 16);
            k1 = *(const uint4*)(kp + base + (size_t)key * 16 + 8);
            v0 = *(const uint4*)(vp + base + (size_t)key * 16);
            v1 = *(const uint4*)(vp + base + (size_t)key * 16 + 8);
        } else {
            k1.w = 0xC61C0000u;            // elem15 = bf16(-10000) sentinel
        }
        *(uint4*)&Kl[key * 24] = k0;
        *(uint4*)&Kl[key * 24 + 8] = k1;
        unsigned short vs[8];
        *(uint4*)vs = v0;
        #pragma unroll
        for (int d = 0; d < 8; d++) Vt[d * 296 + key] = vs[d];
        *(uint4*)vs = v1;
        #pragma unroll
        for (int d = 0; d < 8; d++) Vt[(d + 8) * 296 + key] = vs[d];
    }
    __syncthreads();

    unsigned short* Pw = &Pl[wave][0];
    for (int qt = wave; qt < 17; qt += 4) {
        const int qrow = qt * 16 + lr;
        bf16x8 aq = {0, 0, 0, 0, 0, 0, 0, 0};
        if (lq < 2)
            aq = *(const bf16x8*)(qp + base + (size_t)qrow * 16 + lq * 8);
        for (int kt = 0; kt < 18; kt++) {
            bf16x8 bk = {0, 0, 0, 0, 0, 0, 0, 0};
            if (lq < 2)
                bk = *(const bf16x8*)&Kl[(kt * 16 + lr) * 24 + lq * 8];
            f32x4 sacc = {0.f, 0.f, 0.f, 0.f};
            sacc = __builtin_amdgcn_mfma_f32_16x16x32_bf16(aq, bk, sacc, 0, 0, 0);
            #pragma unroll
            for (int r = 0; r < 4; r++)
                Pw[(lq * 4 + r) * 296 + kt * 16 + lr] = f2h(exp2f(sacc[r]));
        }
        asm volatile("s_waitcnt lgkmcnt(0)" ::: "memory");
        f32x4 o = {0.f, 0.f, 0.f, 0.f};
        #pragma unroll
        for (int ks = 0; ks < 9; ks++) {
            f16x8 ap = *(const f16x8*)&Pw[lr * 296 + ks * 32 + lq * 8];
            f16x8 bv = *(const f16x8*)&Vt[lr * 296 + ks * 32 + lq * 8];
            o = __builtin_amdgcn_mfma_f32_16x16x32_f16(ap, bv, o, 0, 0, 0);
        }
        asm volatile("s_waitcnt lgkmcnt(0)" ::: "memory");
        #pragma unroll
        for (int r = 0; r < 4; r++) {
            float denom = __shfl(o[r], lane | 15);
            int q = qt * 16 + lq * 4 + r;
            if (q < LP_ && lr < 15)
                obf[((size_t)b * LP_ + q) * 256 + hh * DK_ + lr] = f2bf(o[r] / denom);
        }
    }
    // zero pad cols 240..255 (once per row, by hh==0 block)
    if (hh == 0) {
        for (int q = tid; q < LP_; q += 256) {
            uint4 z = {0u, 0u, 0u, 0u};
            *(uint4*)(obf + ((size_t)b * LP_ + q) * 256 + 240) = z;
            *(uint4*)(obf + ((size_t)b * LP_ + q) * 256 + 248) = z;
        }
    }
}

// ---------------- masked mean pool (2-stage) ---------------------------------
__global__ void pool_partial(const float* __restrict__ h, const float* __restrict__ mask,
                             float* __restrict__ partial) {
    int b = blockIdx.x, slice = blockIdx.y;
    int d = threadIdx.x;
    if (d >= D_) return;
    float s = 0.f;
    int l0 = slice * 29;
    for (int i = 0; i < 29; i++) {
        int l = l0 + i;
        if (l < LP_ && mask[b * LP_ + l] == 0.f)
            s += h[((size_t)b * LP_ + l) * D_ + d];
    }
    partial[((size_t)b * 9 + slice) * D_ + d] = s;
}

__global__ void pool_final(const float* __restrict__ partial, const float* __restrict__ mask,
                           float* __restrict__ pool) {
    int b = blockIdx.x;
    int t = threadIdx.x;
    __shared__ float red[256];
    float c = 0.f;
    for (int l = t; l < LP_; l += 256) c += (mask[b * LP_ + l] == 0.f) ? 1.f : 0.f;
    red[t] = c;
    __syncthreads();
    for (int off = 128; off > 0; off >>= 1) {
        if (t < off) red[t] += red[t + off];
        __syncthreads();
    }
    float inv = 1.f / red[0];
    if (t < D_) {
        float s = 0.f;
        #pragma unroll
        for (int sl = 0; sl < 9; sl++) s += partial[((size_t)b * 9 + sl) * D_ + t];
        pool[b * D_ + t] = s * inv;
    }
}

// ---------------- logits -----------------------------------------------------
__global__ void logits_kernel(const float* __restrict__ pool, const float* __restrict__ W,
                              const float* __restrict__ bias, float* __restrict__ out) {
    int idx = blockIdx.x * blockDim.x + threadIdx.x;
    if (idx >= B_ * NC_) return;
    int b = idx / NC_, n = idx - b * NC_;
    float s = bias[n];
    const float* p = pool + b * D_;
    for (int kk = 0; kk < D_; kk++) s += p[kk] * W[(size_t)kk * NC_ + n];
    out[idx] = s;
}

extern "C" void kernel_launch(void* const* d_in, const int* in_sizes, int n_in,
                              void* d_out, int out_size, void* d_ws, size_t ws_size,
                              hipStream_t stream) {
    const float* x        = (const float*)d_in[0];
    const float* pos      = (const float*)d_in[1];
    const float* cls      = (const float*)d_in[2];
    const float* e_W1     = (const float*)d_in[3];
    const float* e_b1     = (const float*)d_in[4];
    const float* e_g1     = (const float*)d_in[5];
    const float* e_bn1    = (const float*)d_in[6];
    const float* e_W2     = (const float*)d_in[7];
    const float* e_b2     = (const float*)d_in[8];
    const float* e_g2     = (const float*)d_in[9];
    const float* e_bn2    = (const float*)d_in[10];
    const float* ln1_g    = (const float*)d_in[11];
    const float* ln1_b    = (const float*)d_in[12];
    const float* Wq       = (const float*)d_in[13];
    const float* bq       = (const float*)d_in[14];
    const float* Wk       = (const float*)d_in[15];
    const float* bk       = (const float*)d_in[16];
    const float* Wv       = (const float*)d_in[17];
    const float* bv       = (const float*)d_in[18];
    const float* Wo       = (const float*)d_in[19];
    const float* bo       = (const float*)d_in[20];
    const float* ln2_g    = (const float*)d_in[21];
    const float* ln2_b    = (const float*)d_in[22];
    const float* W1       = (const float*)d_in[23];
    const float* b1       = (const float*)d_in[24];
    const float* W2       = (const float*)d_in[25];
    const float* b2       = (const float*)d_in[26];
    const float* logit_W  = (const float*)d_in[27];
    const float* logit_b  = (const float*)d_in[28];
    float* out = (float*)d_out;

    const size_t TOK  = (size_t)B_ * LP_;            // 8224
    const size_t TOKP = 8320;                        // padded to 65*128
    const size_t HN   = TOK * D_;
    const size_t QN   = (size_t)B_ * H_ * LP_ * 16;  // 2,105,344

    char* wsb = (char*)d_ws;
    size_t cur = 0;
    auto take = [&](size_t bytes) { void* p = wsb + cur; cur += (bytes + 15) & ~15ULL; return p; };
    float* mask = (float*)take(8224 * 4);
    float* h    = (float*)take(HN * 4);
    float* b720 = (float*)take(NB_ * 720 * 4);
    float* pl   = (float*)take(B_ * D_ * 4);
    float* part = (float*)take((size_t)B_ * 9 * D_ * 4);
    void* regionA = take((size_t)8192 * 480 * 4);
    float* tmp1 = (float*)regionA;
    unsigned short* tbf = (unsigned short*)regionA;
    void* regionB = take(TOKP * 256 * 2 * 2);
    float* y32 = (float*)regionB;
    unsigned short* ybf = (unsigned short*)regionB;
    unsigned short* obf = ybf + TOKP * 256;
    unsigned short* xbf  = (unsigned short*)take((size_t)8192 * 192 * 2);
    unsigned short* We1  = (unsigned short*)take((size_t)512 * 192 * 2);
    unsigned short* We2  = (unsigned short*)take((size_t)256 * 480 * 2);
    unsigned short* Wqkv = (unsigned short*)take((size_t)NB_ * 768 * 256 * 2);
    unsigned short* WoT  = (unsigned short*)take((size_t)NB_ * 256 * 256 * 2);
    unsigned short* W1T  = (unsigned short*)take((size_t)NB_ * 512 * 256 * 2);
    unsigned short* W2T  = (unsigned short*)take((size_t)NB_ * 256 * 480 * 2);
    unsigned short* qp = (unsigned short*)take(QN * 3 * 2 + 16 * 16 * 2);
    unsigned short* kp = qp + QN;
    unsigned short* vp = kp + QN;
    unsigned short* t480bf = qp;   // aliases qp/kp, dead before attn_init

    const int BS = 256;
    auto blocks = [](size_t n) { return (int)((n + 255) / 256); };

    // prep
    mask_kernel<<<blocks(TOK), BS, 0, stream>>>(x, mask);
    pack_bias<<<NB_, BS, 0, stream>>>(bq, bk, bv, b720);
    cvt_x<<<8192, 64, 0, stream>>>(x, xbf);
    pretrans<<<dim3(480, 1), 64, 0, stream>>>(e_W1, We1, PD_, 480, 192, 0, 0);
    pretrans<<<dim3(240, 1), 64, 0, stream>>>(e_W2, We2, 480, 240, 480, 0, 0);
    pretrans<<<dim3(240, NB_), 64, 0, stream>>>(Wq, Wqkv,           240, 240, 256, 240*240, 768*256);
    pretrans<<<dim3(240, NB_), 64, 0, stream>>>(Wk, Wqkv + 240*256, 240, 240, 256, 240*240, 768*256);
    pretrans<<<dim3(240, NB_), 64, 0, stream>>>(Wv, Wqkv + 480*256, 240, 240, 256, 240*240, 768*256);
    pretrans<<<dim3(256, NB_), 64, 0, stream>>>(Wo, WoT,            240, 240, 256, 240*240, 256*256);
    pretrans<<<dim3(480, NB_), 64, 0, stream>>>(W1, W1T,            240, 480, 256, 240*480, 512*256);
    pretrans<<<dim3(256, NB_), 64, 0, stream>>>(W2, W2T,            480, 240, 480, 480*240, 256*480);

    // embed
    gemm_mfma<<<dim3(64, 8), BS, 0, stream>>>(xbf, We1, e_b1, tmp1, nullptr,
                                              nullptr, nullptr, nullptr,
                                              8192, 480, 192, 480, 0);
    ln480<<<2048, BS, 0, stream>>>(tmp1, t480bf, e_g1, e_bn1);
    gemm_mfma<<<dim3(64, 4), BS, 0, stream>>>(t480bf, We2, e_b2, y32, nullptr,
                                              nullptr, nullptr, nullptr,
                                              8192, 240, 480, 240, 0);
    embed_finish<<<(int)TOK, BS, 0, stream>>>(y32, e_g2, e_bn2, pos, cls, h);
    attn_init<<<blocks((size_t)B_ * H_ * LP_), BS, 0, stream>>>(mask, qp, kp, vp);

    for (int i = 0; i < NB_; i++) {
        ln240<<<(int)(TOK / 4), BS, 0, stream>>>(h, ybf, ln1_g + i * D_, ln1_b + i * D_);
        gemm_mfma<<<dim3(65, 12), BS, 0, stream>>>(ybf, Wqkv + (size_t)i * 768 * 256,
                                                   b720 + i * 720, nullptr, nullptr,
                                                   qp, kp, vp,
                                                   (int)TOK, 720, 256, 0, 4);
        attn_mfma<<<dim3(H_, B_), BS, 0, stream>>>(qp, kp, vp, obf);
        gemm_mfma<<<dim3(65, 4, 2), BS, 0, stream>>>(obf, WoT + (size_t)i * 256 * 256,
                                                     bo + i * D_, h, nullptr,
                                                     nullptr, nullptr, nullptr,
                                                     (int)TOK, 240, 256, 240, 2);
        ln240<<<(int)(TOK / 4), BS, 0, stream>>>(h, ybf, ln2_g + i * D_, ln2_b + i * D_);
        gemm_mfma<<<dim3(65, 8), BS, 0, stream>>>(ybf, W1T + (size_t)i * 512 * 256,
                                                  b1 + i * HID_, nullptr, tbf,
                                                  nullptr, nullptr, nullptr,
                                                  (int)TOK, 480, 256, 480, 1 | 8);
        gemm_mfma<<<dim3(65, 4, 2), BS, 0, stream>>>(tbf, W2T + (size_t)i * 256 * 480,
                                                     b2 + i * D_, h, nullptr,
                                                     nullptr, nullptr, nullptr,
                                                     (int)TOK, 240, 480, 240, 2);
    }

    pool_partial<<<dim3(B_, 9), BS, 0, stream>>>(h, mask, part);
    pool_final<<<B_, BS, 0, stream>>>(part, mask, pl);
    logits_kernel<<<blocks((size_t)B_ * NC_), BS, 0, stream>>>(pl, logit_W, logit_b, out);
}

// Round 12
// 869.822 us; speedup vs baseline: 1.3066x; 1.0475x over previous
//
#include <hip/hip_runtime.h>
#include <math.h>

#define B_  32
#define L_  256
#define PD_ 164
#define D_  240
#define H_  16
#define NB_ 6
#define NC_ 250
#define DK_ 15
#define HID_ 480
#define LP_ 257
#define KP_ 288            // keys padded to 9*32
#define SCALE_ 0.2581988897471611f   // 1/sqrt(15)
#define LOG2E_ 1.4426950408889634f

typedef __attribute__((ext_vector_type(8))) short bf16x8;
typedef __attribute__((ext_vector_type(8))) _Float16 f16x8;
typedef __attribute__((ext_vector_type(4))) float f32x4;

static __device__ inline unsigned short f2bf(float x) {
    unsigned u = __builtin_bit_cast(unsigned, x);
    u += 0x7FFFu + ((u >> 16) & 1u);     // RNE (finite values only)
    return (unsigned short)(u >> 16);
}
static __device__ inline unsigned short f2h(float x) {
    _Float16 h = (_Float16)x;
    return __builtin_bit_cast(unsigned short, h);
}

// async global->LDS, 16B per lane; lds dest must be wave-uniform base (+lane*16)
static __device__ inline void gl2lds16(const void* g, void* l) {
    __builtin_amdgcn_global_load_lds(
        (const __attribute__((address_space(1))) unsigned int*)g,
        (__attribute__((address_space(3))) unsigned int*)l, 16, 0, 0);
}

// --------- prep_misc: cvt_x (0..8191) + pack_bias (8192..8197) + mask --------
__global__ void prep_misc(const float* __restrict__ x, unsigned short* __restrict__ xbf,
                          const float* __restrict__ bq, const float* __restrict__ bk,
                          const float* __restrict__ bv, float* __restrict__ b720,
                          float* __restrict__ mask) {
    int u = blockIdx.x;
    if (u < 8192) {
        const float* src = x + (size_t)u * PD_;
        unsigned short* dst = xbf + (size_t)u * 192;
        for (int k = threadIdx.x; k < 192; k += 64)
            dst[k] = f2bf(k < PD_ ? src[k] : 0.f);
    } else if (u < 8192 + NB_) {
        int i = u - 8192;
        for (int n = threadIdx.x; n < 720; n += 64) {
            float v = (n < 240) ? bq[i * 240 + n]
                    : (n < 480) ? bk[i * 240 + n - 240]
                                : bv[i * 240 + n - 480];
            b720[i * 720 + n] = v;
        }
    } else {
        int idx = (u - 8192 - NB_) * 64 + threadIdx.x;
        if (idx >= B_ * LP_) return;
        int b = idx / LP_, l = idx % LP_;
        if (l == 0) { mask[idx] = 0.f; return; }
        const float* xr = x + ((size_t)b * L_ + (l - 1)) * PD_;
        float mx = -1e30f;
        for (int j = 0; j < PD_; j++) mx = fmaxf(mx, xr[j]);
        mask[idx] = (mx == 0.f) ? 1.f : 0.f;
    }
}

// --------- prep_weights: all 38 pretranspose jobs in one dispatch ------------
// grid (480, 38): y = job, x = output column n; 64 threads
__global__ void prep_weights(const float* __restrict__ e_W1, const float* __restrict__ e_W2,
                             const float* __restrict__ Wq, const float* __restrict__ Wk,
                             const float* __restrict__ Wv, const float* __restrict__ Wo,
                             const float* __restrict__ W1, const float* __restrict__ W2,
                             unsigned short* __restrict__ We1, unsigned short* __restrict__ We2,
                             unsigned short* __restrict__ Wqkv, unsigned short* __restrict__ WoT,
                             unsigned short* __restrict__ W1T, unsigned short* __restrict__ W2T) {
    int job = blockIdx.y, n = blockIdx.x;
    const float* src; unsigned short* dst; int K, N, Kpad;
    if (job == 0)      { src = e_W1; dst = We1; K = PD_; N = 480; Kpad = 192; }
    else if (job == 1) { src = e_W2; dst = We2; K = 480; N = 240; Kpad = 480; }
    else {
        int i = (job - 2) % 6, w = (job - 2) / 6;
        if (w == 0)      { src = Wq + (size_t)i*240*240; dst = Wqkv + (size_t)i*768*256;           K=240; N=240; Kpad=256; }
        else if (w == 1) { src = Wk + (size_t)i*240*240; dst = Wqkv + (size_t)i*768*256 + 240*256; K=240; N=240; Kpad=256; }
        else if (w == 2) { src = Wv + (size_t)i*240*240; dst = Wqkv + (size_t)i*768*256 + 480*256; K=240; N=240; Kpad=256; }
        else if (w == 3) { src = Wo + (size_t)i*240*240; dst = WoT + (size_t)i*256*256;            K=240; N=256; Kpad=256; }
        else if (w == 4) { src = W1 + (size_t)i*240*480; dst = W1T + (size_t)i*512*256;            K=240; N=480; Kpad=256; }
        else             { src = W2 + (size_t)i*480*240; dst = W2T + (size_t)i*256*480;            K=480; N=256; Kpad=480; }
    }
    if (n >= N) return;
    // for padded rows (n >= real N) the k<K&&n<realN test below writes zeros
    int realN = (N == 256) ? 240 : N;
    unsigned short* d = dst + (size_t)n * Kpad;
    for (int k = threadIdx.x; k < Kpad; k += 64)
        d[k] = f2bf((k < K && n < realN) ? src[(size_t)k * realN + n] : 0.f);
}

// ---------------- MFMA GEMM: C = A[M,Kpad]bf16 @ Bt[N,Kpad]bf16 --------------
// tile 128x64, 4 waves (2x2), K-step 32. Staging via global_load_lds.
// Optional K-split via gridDim.z (flags&2 path -> atomicAdd). Bias by z==0.
// flags: 1 relu, 2 accumulate fp32 C, 4 QKV-packed epilogue, 8 bf16 out
__global__ __launch_bounds__(256)
void gemm_mfma(const unsigned short* __restrict__ A,
               const unsigned short* __restrict__ Bt,
               const float* __restrict__ bias,
               float* __restrict__ C, unsigned short* __restrict__ Cbf,
               unsigned short* __restrict__ qp, unsigned short* __restrict__ kp,
               unsigned short* __restrict__ vp,
               int M, int N, int Kpad, int Cstride, int flags)
{
    __shared__ __align__(16) unsigned short As[128 * 32];   // 8 KB
    __shared__ __align__(16) unsigned short Bs[64 * 32];    // 4 KB
    const int tid = threadIdx.x;
    const int bm = blockIdx.x * 128;
    const int bn = blockIdx.y * 64;
    const int zs = gridDim.z, zi = blockIdx.z;
    const int wave = tid >> 6, lane = tid & 63;
    const int wm = (wave & 1) * 64, wn = (wave >> 1) * 32;
    const int lq = lane >> 4, lr = lane & 15;

    f32x4 acc[4][2];
    #pragma unroll
    for (int i = 0; i < 4; i++)
        #pragma unroll
        for (int j = 0; j < 2; j++) acc[i][j] = (f32x4){0.f, 0.f, 0.f, 0.f};

    const int srow = lane >> 2;            // 0..15
    const int schk = (lane & 3) << 3;      // 0,8,16,24
    const int nkt = Kpad >> 5;
    const int kt0 = (nkt * zi) / zs;
    const int kt1 = (nkt * (zi + 1)) / zs;

    const unsigned short* ga0 = A + (size_t)(bm + wave * 32 + srow) * Kpad + schk + kt0 * 32;
    const unsigned short* ga1 = A + (size_t)(bm + wave * 32 + 16 + srow) * Kpad + schk + kt0 * 32;
    const unsigned short* gb  = Bt + (size_t)(bn + wave * 16 + srow) * Kpad + schk + kt0 * 32;
    char* la0 = (char*)As + wave * 2048;
    char* la1 = (char*)As + wave * 2048 + 1024;
    char* lb  = (char*)Bs + wave * 1024;

    for (int kt = kt0; kt < kt1; kt++) {
        gl2lds16(ga0, la0);
        gl2lds16(ga1, la1);
        gl2lds16(gb, lb);
        ga0 += 32; ga1 += 32; gb += 32;
        __syncthreads();
        bf16x8 af[4], bfr[2];
        #pragma unroll
        for (int i = 0; i < 4; i++)
            af[i] = *(const bf16x8*)&As[(wm + i * 16 + lr) * 32 + lq * 8];
        #pragma unroll
        for (int j = 0; j < 2; j++)
            bfr[j] = *(const bf16x8*)&Bs[(wn + j * 16 + lr) * 32 + lq * 8];
        #pragma unroll
        for (int i = 0; i < 4; i++)
            #pragma unroll
            for (int j = 0; j < 2; j++)
                acc[i][j] = __builtin_amdgcn_mfma_f32_16x16x32_bf16(af[i], bfr[j], acc[i][j], 0, 0, 0);
        __syncthreads();
    }

    if (flags & 4) {                       // QKV packed epilogue (N=720)
        #pragma unroll
        for (int j = 0; j < 2; j++) {
            int n = bn + wn + j * 16 + lr;
            if (n >= N) continue;
            int which = n / 240;
            int rem = n - which * 240;
            int hh = rem / 15;
            int c = rem - hh * 15;
            unsigned short* dst = (which == 0) ? qp : (which == 1) ? kp : vp;
            float bias_n = bias[n];
            float mult = (which == 0) ? (SCALE_ * LOG2E_) : 1.f;
            #pragma unroll
            for (int i = 0; i < 4; i++)
                #pragma unroll
                for (int r = 0; r < 4; r++) {
                    int m = bm + wm + i * 16 + lq * 4 + r;
                    if (m >= M) continue;
                    float s = (acc[i][j][r] + bias_n) * mult;
                    int b = m / LP_, l = m - b * LP_;
                    unsigned short bits = (which == 2) ? f2h(s) : f2bf(s);
                    dst[(((size_t)b * H_ + hh) * LP_ + l) * 16 + c] = bits;
                }
        }
    } else if (flags & 8) {                // bf16 output
        #pragma unroll
        for (int i = 0; i < 4; i++)
            #pragma unroll
            for (int j = 0; j < 2; j++) {
                int n = bn + wn + j * 16 + lr;
                if (n >= N) continue;
                float bias_n = bias ? bias[n] : 0.f;
                #pragma unroll
                for (int r = 0; r < 4; r++) {
                    int m = bm + wm + i * 16 + lq * 4 + r;
                    if (m >= M) continue;
                    float s = acc[i][j][r] + bias_n;
                    if (flags & 1) s = fmaxf(s, 0.f);
                    Cbf[(size_t)m * Cstride + n] = f2bf(s);
                }
            }
    } else {                               // fp32 output (optionally accumulate)
        #pragma unroll
        for (int i = 0; i < 4; i++)
            #pragma unroll
            for (int j = 0; j < 2; j++) {
                int n = bn + wn + j * 16 + lr;
                if (n >= N) continue;
                float bias_n = (bias && zi == 0) ? bias[n] : 0.f;
                #pragma unroll
                for (int r = 0; r < 4; r++) {
                    int m = bm + wm + i * 16 + lq * 4 + r;
                    if (m >= M) continue;
                    float s = acc[i][j][r] + bias_n;
                    if (flags & 1) s = fmaxf(s, 0.f);
                    size_t off = (size_t)m * Cstride + n;
                    if (flags & 2) {
                        if (zs > 1) atomicAdd(&C[off], s);
                        else C[off] += s;
                    } else C[off] = s;
                }
            }
    }
}

// ------------- LN240: wave-per-row, fp32 in -> bf16 out [rows][256] ----------
__global__ __launch_bounds__(256)
void ln240(const float* __restrict__ in, unsigned short* __restrict__ out,
           const float* __restrict__ g, const float* __restrict__ bb) {
    const int row = blockIdx.x * 4 + (threadIdx.x >> 6);
    const int lane = threadIdx.x & 63;
    const float* x = in + (size_t)row * 240;
    float4 v = {0.f, 0.f, 0.f, 0.f};
    if (lane < 60) v = *(const float4*)(x + lane * 4);
    float s = (v.x + v.y) + (v.z + v.w);
    #pragma unroll
    for (int off = 32; off; off >>= 1) s += __shfl_xor(s, off);
    const float mean = s * (1.f / 240.f);
    float4 d;
    d.x = v.x - mean; d.y = v.y - mean; d.z = v.z - mean; d.w = v.w - mean;
    float vs = (lane < 60) ? (d.x * d.x + d.y * d.y) + (d.z * d.z + d.w * d.w) : 0.f;
    #pragma unroll
    for (int off = 32; off; off >>= 1) vs += __shfl_xor(vs, off);
    const float rs = rsqrtf(vs * (1.f / 240.f) + 1e-5f);
    ushort4 o4 = {0, 0, 0, 0};
    if (lane < 60) {
        float4 g4 = *(const float4*)(g + lane * 4);
        float4 b4 = *(const float4*)(bb + lane * 4);
        o4.x = f2bf(d.x * rs * g4.x + b4.x);
        o4.y = f2bf(d.y * rs * g4.y + b4.y);
        o4.z = f2bf(d.z * rs * g4.z + b4.z);
        o4.w = f2bf(d.w * rs * g4.w + b4.w);
    }
    *(ushort4*)(out + (size_t)row * 256 + lane * 4) = o4;   // lanes 60..63: pad zeros
}

// ------------- LN480+relu: wave-per-row, fp32 in -> bf16 out [rows][480] -----
__global__ __launch_bounds__(256)
void ln480(const float* __restrict__ in, unsigned short* __restrict__ out,
           const float* __restrict__ g, const float* __restrict__ bb) {
    const int row = blockIdx.x * 4 + (threadIdx.x >> 6);
    const int lane = threadIdx.x & 63;
    const float* x = in + (size_t)row * 480;
    float4 va = {0.f,0.f,0.f,0.f}, vb = {0.f,0.f,0.f,0.f};
    if (lane < 60) {
        va = *(const float4*)(x + lane * 8);
        vb = *(const float4*)(x + lane * 8 + 4);
    }
    float s = ((va.x + va.y) + (va.z + va.w)) + ((vb.x + vb.y) + (vb.z + vb.w));
    #pragma unroll
    for (int off = 32; off; off >>= 1) s += __shfl_xor(s, off);
    const float mean = s * (1.f / 480.f);
    float4 da, db;
    da.x = va.x - mean; da.y = va.y - mean; da.z = va.z - mean; da.w = va.w - mean;
    db.x = vb.x - mean; db.y = vb.y - mean; db.z = vb.z - mean; db.w = vb.w - mean;
    float vs = (lane < 60) ? ((da.x*da.x + da.y*da.y) + (da.z*da.z + da.w*da.w)) +
                             ((db.x*db.x + db.y*db.y) + (db.z*db.z + db.w*db.w)) : 0.f;
    #pragma unroll
    for (int off = 32; off; off >>= 1) vs += __shfl_xor(vs, off);
    const float rs = rsqrtf(vs * (1.f / 480.f) + 1e-5f);
    if (lane < 60) {
        float4 ga = *(const float4*)(g + lane * 8);
        float4 gb = *(const float4*)(g + lane * 8 + 4);
        float4 ba = *(const float4*)(bb + lane * 8);
        float4 b2 = *(const float4*)(bb + lane * 8 + 4);
        ushort4 oa, ob;
        oa.x = f2bf(fmaxf(da.x * rs * ga.x + ba.x, 0.f));
        oa.y = f2bf(fmaxf(da.y * rs * ga.y + ba.y, 0.f));
        oa.z = f2bf(fmaxf(da.z * rs * ga.z + ba.z, 0.f));
        oa.w = f2bf(fmaxf(da.w * rs * ga.w + ba.w, 0.f));
        ob.x = f2bf(fmaxf(db.x * rs * gb.x + b2.x, 0.f));
        ob.y = f2bf(fmaxf(db.y * rs * gb.y + b2.y, 0.f));
        ob.z = f2bf(fmaxf(db.z * rs * gb.z + b2.z, 0.f));
        ob.w = f2bf(fmaxf(db.w * rs * gb.w + b2.w, 0.f));
        *(ushort4*)(out + (size_t)row * 480 + lane * 8) = oa;
        *(ushort4*)(out + (size_t)row * 480 + lane * 8 + 4) = ob;
    }
}

// -------- embed finish: wave-per-row LN(g2)+relu+pos (cls for l==0) ----------
// lanes 60..62 also write q/k/v col-15 constants (replaces attn_init).
__global__ __launch_bounds__(256)
void embed_finish(const float* __restrict__ tmp, const float* __restrict__ mask,
                  const float* __restrict__ g, const float* __restrict__ bb,
                  const float* __restrict__ pos, const float* __restrict__ cls,
                  float* __restrict__ h,
                  unsigned short* __restrict__ qp, unsigned short* __restrict__ kp,
                  unsigned short* __restrict__ vp) {
    const int row = blockIdx.x * 4 + (threadIdx.x >> 6);
    const int lane = threadIdx.x & 63;
    const int b = row / LP_, l = row - b * LP_;
    float* outr = h + (size_t)row * 240;

    if (lane >= 60 && lane <= 62) {
        unsigned short bits;
        unsigned short* dst;
        if (lane == 60) { bits = f2bf(LOG2E_); dst = qp; }
        else if (lane == 61) { bits = (mask[row] != 0.f) ? f2bf(-10000.f) : 0; dst = kp; }
        else { bits = f2h(1.f); dst = vp; }
        #pragma unroll
        for (int hh = 0; hh < H_; hh++)
            dst[(((size_t)b * H_ + hh) * LP_ + l) * 16 + 15] = bits;
    }

    if (l == 0) {
        if (lane < 60) *(float4*)(outr + lane * 4) = *(const float4*)(cls + lane * 4);
        return;
    }
    const float* x = tmp + ((size_t)b * L_ + (l - 1)) * 240;
    float4 v = {0.f, 0.f, 0.f, 0.f};
    if (lane < 60) v = *(const float4*)(x + lane * 4);
    float s = (v.x + v.y) + (v.z + v.w);
    #pragma unroll
    for (int off = 32; off; off >>= 1) s += __shfl_xor(s, off);
    const float mean = s * (1.f / 240.f);
    float4 d;
    d.x = v.x - mean; d.y = v.y - mean; d.z = v.z - mean; d.w = v.w - mean;
    float vs = (lane < 60) ? (d.x * d.x + d.y * d.y) + (d.z * d.z + d.w * d.w) : 0.f;
    #pragma unroll
    for (int off = 32; off; off >>= 1) vs += __shfl_xor(vs, off);
    const float rs = rsqrtf(vs * (1.f / 240.f) + 1e-5f);
    if (lane < 60) {
        float4 g4 = *(const float4*)(g + lane * 4);
        float4 b4 = *(const float4*)(bb + lane * 4);
        float4 p4 = *(const float4*)(pos + (size_t)(l - 1) * 240 + lane * 4);
        float4 o;
        o.x = fmaxf(d.x * rs * g4.x + b4.x, 0.f) + p4.x;
        o.y = fmaxf(d.y * rs * g4.y + b4.y, 0.f) + p4.y;
        o.z = fmaxf(d.z * rs * g4.z + b4.z, 0.f) + p4.z;
        o.w = fmaxf(d.w * rs * g4.w + b4.w, 0.f) + p4.w;
        *(float4*)(outr + lane * 4) = o;
    }
}

// ---------------- MFMA flash attention: block per (b,h), 4 waves -------------
__global__ __launch_bounds__(256)
void attn_mfma(const unsigned short* __restrict__ qp, const unsigned short* __restrict__ kp,
               const unsigned short* __restrict__ vp, unsigned short* __restrict__ obf)
{
    __shared__ __align__(16) unsigned short Kl[KP_ * 24];    // 13.5 KB
    __shared__ __align__(16) unsigned short Vt[16 * 296];    // 9.25 KB  V^T f16
    __shared__ __align__(16) unsigned short Pl[4][16 * 296]; // 37 KB    P f16 per wave
    const int hh = blockIdx.x, b = blockIdx.y;
    const int tid = threadIdx.x;
    const int wave = tid >> 6, lane = tid & 63;
    const int lq = lane >> 4, lr = lane & 15;
    const size_t base = ((size_t)b * H_ + hh) * LP_ * 16;

    for (int key = tid; key < KP_; key += 256) {
        uint4 z = {0u, 0u, 0u, 0u};
        uint4 k0 = z, k1 = z, v0 = z, v1 = z;
        if (key < LP_) {
            k0 = *(const uint4*)(kp + base + (size_t)key * 16);
            k1 = *(const uint4*)(kp + base + (size_t)key * 16 + 8);
            v0 = *(const uint4*)(vp + base + (size_t)key * 16);
            v1 = *(const uint4*)(vp + base + (size_t)key * 16 + 8);
        } else {
            k1.w = 0xC61C0000u;            // elem15 = bf16(-10000) sentinel
        }
        *(uint4*)&Kl[key * 24] = k0;
        *(uint4*)&Kl[key * 24 + 8] = k1;
        unsigned short vs[8];
        *(uint4*)vs = v0;
        #pragma unroll
        for (int d = 0; d < 8; d++) Vt[d * 296 + key] = vs[d];
        *(uint4*)vs = v1;
        #pragma unroll
        for (int d = 0; d < 8; d++) Vt[(d + 8) * 296 + key] = vs[d];
    }
    __syncthreads();

    unsigned short* Pw = &Pl[wave][0];
    for (int qt = wave; qt < 17; qt += 4) {
        const int qrow = qt * 16 + lr;
        bf16x8 aq = {0, 0, 0, 0, 0, 0, 0, 0};
        if (lq < 2)
            aq = *(const bf16x8*)(qp + base + (size_t)qrow * 16 + lq * 8);
        for (int kt = 0; kt < 18; kt++) {
            bf16x8 bk = {0, 0, 0, 0, 0, 0, 0, 0};
            if (lq < 2)
                bk = *(const bf16x8*)&Kl[(kt * 16 + lr) * 24 + lq * 8];
            f32x4 sacc = {0.f, 0.f, 0.f, 0.f};
            sacc = __builtin_amdgcn_mfma_f32_16x16x32_bf16(aq, bk, sacc, 0, 0, 0);
            #pragma unroll
            for (int r = 0; r < 4; r++)
                Pw[(lq * 4 + r) * 296 + kt * 16 + lr] = f2h(exp2f(sacc[r]));
        }
        asm volatile("s_waitcnt lgkmcnt(0)" ::: "memory");
        f32x4 o = {0.f, 0.f, 0.f, 0.f};
        #pragma unroll
        for (int ks = 0; ks < 9; ks++) {
            f16x8 ap = *(const f16x8*)&Pw[lr * 296 + ks * 32 + lq * 8];
            f16x8 bv = *(const f16x8*)&Vt[lr * 296 + ks * 32 + lq * 8];
            o = __builtin_amdgcn_mfma_f32_16x16x32_f16(ap, bv, o, 0, 0, 0);
        }
        asm volatile("s_waitcnt lgkmcnt(0)" ::: "memory");
        #pragma unroll
        for (int r = 0; r < 4; r++) {
            float denom = __shfl(o[r], lane | 15);
            int q = qt * 16 + lq * 4 + r;
            if (q < LP_ && lr < 15)
                obf[((size_t)b * LP_ + q) * 256 + hh * DK_ + lr] = f2bf(o[r] / denom);
        }
    }
    // zero pad cols 240..255 (once per row, by hh==0 block)
    if (hh == 0) {
        for (int q = tid; q < LP_; q += 256) {
            uint4 z = {0u, 0u, 0u, 0u};
            *(uint4*)(obf + ((size_t)b * LP_ + q) * 256 + 240) = z;
            *(uint4*)(obf + ((size_t)b * LP_ + q) * 256 + 248) = z;
        }
    }
}

// ---------------- masked mean pool (2-stage) ---------------------------------
__global__ void pool_partial(const float* __restrict__ h, const float* __restrict__ mask,
                             float* __restrict__ partial) {
    int b = blockIdx.x, slice = blockIdx.y;
    int d = threadIdx.x;
    if (d >= D_) return;
    float s = 0.f;
    int l0 = slice * 29;
    for (int i = 0; i < 29; i++) {
        int l = l0 + i;
        if (l < LP_ && mask[b * LP_ + l] == 0.f)
            s += h[((size_t)b * LP_ + l) * D_ + d];
    }
    partial[((size_t)b * 9 + slice) * D_ + d] = s;
}

__global__ void pool_final(const float* __restrict__ partial, const float* __restrict__ mask,
                           float* __restrict__ pool) {
    int b = blockIdx.x;
    int t = threadIdx.x;
    __shared__ float red[256];
    float c = 0.f;
    for (int l = t; l < LP_; l += 256) c += (mask[b * LP_ + l] == 0.f) ? 1.f : 0.f;
    red[t] = c;
    __syncthreads();
    for (int off = 128; off > 0; off >>= 1) {
        if (t < off) red[t] += red[t + off];
        __syncthreads();
    }
    float inv = 1.f / red[0];
    if (t < D_) {
        float s = 0.f;
        #pragma unroll
        for (int sl = 0; sl < 9; sl++) s += partial[((size_t)b * 9 + sl) * D_ + t];
        pool[b * D_ + t] = s * inv;
    }
}

// ---------------- logits -----------------------------------------------------
__global__ void logits_kernel(const float* __restrict__ pool, const float* __restrict__ W,
                              const float* __restrict__ bias, float* __restrict__ out) {
    int idx = blockIdx.x * blockDim.x + threadIdx.x;
    if (idx >= B_ * NC_) return;
    int b = idx / NC_, n = idx - b * NC_;
    float s = bias[n];
    const float* p = pool + b * D_;
    for (int kk = 0; kk < D_; kk++) s += p[kk] * W[(size_t)kk * NC_ + n];
    out[idx] = s;
}

extern "C" void kernel_launch(void* const* d_in, const int* in_sizes, int n_in,
                              void* d_out, int out_size, void* d_ws, size_t ws_size,
                              hipStream_t stream) {
    const float* x        = (const float*)d_in[0];
    const float* pos      = (const float*)d_in[1];
    const float* cls      = (const float*)d_in[2];
    const float* e_W1     = (const float*)d_in[3];
    const float* e_b1     = (const float*)d_in[4];
    const float* e_g1     = (const float*)d_in[5];
    const float* e_bn1    = (const float*)d_in[6];
    const float* e_W2     = (const float*)d_in[7];
    const float* e_b2     = (const float*)d_in[8];
    const float* e_g2     = (const float*)d_in[9];
    const float* e_bn2    = (const float*)d_in[10];
    const float* ln1_g    = (const float*)d_in[11];
    const float* ln1_b    = (const float*)d_in[12];
    const float* Wq       = (const float*)d_in[13];
    const float* bq       = (const float*)d_in[14];
    const float* Wk       = (const float*)d_in[15];
    const float* bk       = (const float*)d_in[16];
    const float* Wv       = (const float*)d_in[17];
    const float* bv       = (const float*)d_in[18];
    const float* Wo       = (const float*)d_in[19];
    const float* bo       = (const float*)d_in[20];
    const float* ln2_g    = (const float*)d_in[21];
    const float* ln2_b    = (const float*)d_in[22];
    const float* W1       = (const float*)d_in[23];
    const float* b1       = (const float*)d_in[24];
    const float* W2       = (const float*)d_in[25];
    const float* b2       = (const float*)d_in[26];
    const float* logit_W  = (const float*)d_in[27];
    const float* logit_b  = (const float*)d_in[28];
    float* out = (float*)d_out;

    const size_t TOK  = (size_t)B_ * LP_;            // 8224
    const size_t TOKP = 8320;                        // padded to 65*128
    const size_t HN   = TOK * D_;
    const size_t QN   = (size_t)B_ * H_ * LP_ * 16;  // 2,105,344

    char* wsb = (char*)d_ws;
    size_t cur = 0;
    auto take = [&](size_t bytes) { void* p = wsb + cur; cur += (bytes + 15) & ~15ULL; return p; };
    float* mask = (float*)take(8224 * 4);
    float* h    = (float*)take(HN * 4);
    float* b720 = (float*)take(NB_ * 720 * 4);
    float* pl   = (float*)take(B_ * D_ * 4);
    float* part = (float*)take((size_t)B_ * 9 * D_ * 4);
    void* regionA = take((size_t)8192 * 480 * 4);
    float* tmp1 = (float*)regionA;
    unsigned short* tbf = (unsigned short*)regionA;
    void* regionB = take(TOKP * 256 * 2 * 2);
    float* y32 = (float*)regionB;
    unsigned short* ybf = (unsigned short*)regionB;
    unsigned short* obf = ybf + TOKP * 256;
    unsigned short* xbf  = (unsigned short*)take((size_t)8192 * 192 * 2);
    unsigned short* We1  = (unsigned short*)take((size_t)512 * 192 * 2);
    unsigned short* We2  = (unsigned short*)take((size_t)256 * 480 * 2);
    unsigned short* Wqkv = (unsigned short*)take((size_t)NB_ * 768 * 256 * 2);
    unsigned short* WoT  = (unsigned short*)take((size_t)NB_ * 256 * 256 * 2);
    unsigned short* W1T  = (unsigned short*)take((size_t)NB_ * 512 * 256 * 2);
    unsigned short* W2T  = (unsigned short*)take((size_t)NB_ * 256 * 480 * 2);
    unsigned short* qp = (unsigned short*)take(QN * 3 * 2 + 16 * 16 * 2);
    unsigned short* kp = qp + QN;
    unsigned short* vp = kp + QN;
    unsigned short* t480bf = qp;   // aliases qp/kp, dead before embed_finish

    const int BS = 256;
    auto blocks = [](size_t n) { return (int)((n + 255) / 256); };

    // prep (2 dispatches)
    prep_misc<<<8192 + NB_ + 129, 64, 0, stream>>>(x, xbf, bq, bk, bv, b720, mask);
    prep_weights<<<dim3(480, 38), 64, 0, stream>>>(e_W1, e_W2, Wq, Wk, Wv, Wo, W1, W2,
                                                   We1, We2, Wqkv, WoT, W1T, W2T);

    // embed
    gemm_mfma<<<dim3(64, 8), BS, 0, stream>>>(xbf, We1, e_b1, tmp1, nullptr,
                                              nullptr, nullptr, nullptr,
                                              8192, 480, 192, 480, 0);
    ln480<<<2048, BS, 0, stream>>>(tmp1, t480bf, e_g1, e_bn1);
    gemm_mfma<<<dim3(64, 4), BS, 0, stream>>>(t480bf, We2, e_b2, y32, nullptr,
                                              nullptr, nullptr, nullptr,
                                              8192, 240, 480, 240, 0);
    embed_finish<<<(int)(TOK / 4), BS, 0, stream>>>(y32, mask, e_g2, e_bn2, pos, cls, h,
                                                    qp, kp, vp);

    for (int i = 0; i < NB_; i++) {
        ln240<<<(int)(TOK / 4), BS, 0, stream>>>(h, ybf, ln1_g + i * D_, ln1_b + i * D_);
        gemm_mfma<<<dim3(65, 12), BS, 0, stream>>>(ybf, Wqkv + (size_t)i * 768 * 256,
                                                   b720 + i * 720, nullptr, nullptr,
                                                   qp, kp, vp,
                                                   (int)TOK, 720, 256, 0, 4);
        attn_mfma<<<dim3(H_, B_), BS, 0, stream>>>(qp, kp, vp, obf);
        gemm_mfma<<<dim3(65, 4, 2), BS, 0, stream>>>(obf, WoT + (size_t)i * 256 * 256,
                                                     bo + i * D_, h, nullptr,
                                                     nullptr, nullptr, nullptr,
                                                     (int)TOK, 240, 256, 240, 2);
        ln240<<<(int)(TOK / 4), BS, 0, stream>>>(h, ybf, ln2_g + i * D_, ln2_b + i * D_);
        gemm_mfma<<<dim3(65, 8), BS, 0, stream>>>(ybf, W1T + (size_t)i * 512 * 256,
                                                  b1 + i * HID_, nullptr, tbf,
                                                  nullptr, nullptr, nullptr,
                                                  (int)TOK, 480, 256, 480, 1 | 8);
        gemm_mfma<<<dim3(65, 4, 2), BS, 0, stream>>>(tbf, W2T + (size_t)i * 256 * 480,
                                                     b2 + i * D_, h, nullptr,
                                                     nullptr, nullptr, nullptr,
                                                     (int)TOK, 240, 480, 240, 2);
    }

    pool_partial<<<dim3(B_, 9), BS, 0, stream>>>(h, mask, part);
    pool_final<<<B_, BS, 0, stream>>>(part, mask, pl);
    logits_kernel<<<blocks((size_t)B_ * NC_), BS, 0, stream>>>(pl, logit_W, logit_b, out);
}

// Round 13
// 861.999 us; speedup vs baseline: 1.3184x; 1.0091x over previous
//
#include <hip/hip_runtime.h>
#include <math.h>

#define B_  32
#define L_  256
#define PD_ 164
#define D_  240
#define H_  16
#define NB_ 6
#define NC_ 250
#define DK_ 15
#define HID_ 480
#define LP_ 257
#define KP_ 288            // keys padded to 9*32
#define SCALE_ 0.2581988897471611f   // 1/sqrt(15)
#define LOG2E_ 1.4426950408889634f

typedef __attribute__((ext_vector_type(8))) short bf16x8;
typedef __attribute__((ext_vector_type(8))) _Float16 f16x8;
typedef __attribute__((ext_vector_type(4))) float f32x4;

static __device__ inline unsigned short f2bf(float x) {
    unsigned u = __builtin_bit_cast(unsigned, x);
    u += 0x7FFFu + ((u >> 16) & 1u);     // RNE (finite values only)
    return (unsigned short)(u >> 16);
}
static __device__ inline unsigned short f2h(float x) {
    _Float16 h = (_Float16)x;
    return __builtin_bit_cast(unsigned short, h);
}

// async global->LDS, 16B per lane; lds dest must be wave-uniform base (+lane*16)
static __device__ inline void gl2lds16(const void* g, void* l) {
    __builtin_amdgcn_global_load_lds(
        (const __attribute__((address_space(1))) unsigned int*)g,
        (__attribute__((address_space(3))) unsigned int*)l, 16, 0, 0);
}

// --------- prep_misc: cvt_x (0..8191) + pack_bias (8192..8197) + mask --------
__global__ void prep_misc(const float* __restrict__ x, unsigned short* __restrict__ xbf,
                          const float* __restrict__ bq, const float* __restrict__ bk,
                          const float* __restrict__ bv, float* __restrict__ b720,
                          float* __restrict__ mask) {
    int u = blockIdx.x;
    if (u < 8192) {
        const float* src = x + (size_t)u * PD_;
        unsigned short* dst = xbf + (size_t)u * 192;
        for (int k = threadIdx.x; k < 192; k += 64)
            dst[k] = f2bf(k < PD_ ? src[k] : 0.f);
    } else if (u < 8192 + NB_) {
        int i = u - 8192;
        for (int n = threadIdx.x; n < 720; n += 64) {
            float v = (n < 240) ? bq[i * 240 + n]
                    : (n < 480) ? bk[i * 240 + n - 240]
                                : bv[i * 240 + n - 480];
            b720[i * 720 + n] = v;
        }
    } else {
        int idx = (u - 8192 - NB_) * 64 + threadIdx.x;
        if (idx >= B_ * LP_) return;
        int b = idx / LP_, l = idx % LP_;
        if (l == 0) { mask[idx] = 0.f; return; }
        const float* xr = x + ((size_t)b * L_ + (l - 1)) * PD_;
        float mx = -1e30f;
        for (int j = 0; j < PD_; j++) mx = fmaxf(mx, xr[j]);
        mask[idx] = (mx == 0.f) ? 1.f : 0.f;
    }
}

// --------- prep_weights: all 38 pretranspose jobs in one dispatch ------------
__global__ void prep_weights(const float* __restrict__ e_W1, const float* __restrict__ e_W2,
                             const float* __restrict__ Wq, const float* __restrict__ Wk,
                             const float* __restrict__ Wv, const float* __restrict__ Wo,
                             const float* __restrict__ W1, const float* __restrict__ W2,
                             unsigned short* __restrict__ We1, unsigned short* __restrict__ We2,
                             unsigned short* __restrict__ Wqkv, unsigned short* __restrict__ WoT,
                             unsigned short* __restrict__ W1T, unsigned short* __restrict__ W2T) {
    int job = blockIdx.y, n = blockIdx.x;
    const float* src; unsigned short* dst; int K, N, Kpad;
    if (job == 0)      { src = e_W1; dst = We1; K = PD_; N = 480; Kpad = 192; }
    else if (job == 1) { src = e_W2; dst = We2; K = 480; N = 240; Kpad = 480; }
    else {
        int i = (job - 2) % 6, w = (job - 2) / 6;
        if (w == 0)      { src = Wq + (size_t)i*240*240; dst = Wqkv + (size_t)i*768*256;           K=240; N=240; Kpad=256; }
        else if (w == 1) { src = Wk + (size_t)i*240*240; dst = Wqkv + (size_t)i*768*256 + 240*256; K=240; N=240; Kpad=256; }
        else if (w == 2) { src = Wv + (size_t)i*240*240; dst = Wqkv + (size_t)i*768*256 + 480*256; K=240; N=240; Kpad=256; }
        else if (w == 3) { src = Wo + (size_t)i*240*240; dst = WoT + (size_t)i*256*256;            K=240; N=256; Kpad=256; }
        else if (w == 4) { src = W1 + (size_t)i*240*480; dst = W1T + (size_t)i*512*256;            K=240; N=480; Kpad=256; }
        else             { src = W2 + (size_t)i*480*240; dst = W2T + (size_t)i*256*480;            K=480; N=256; Kpad=480; }
    }
    if (n >= N) return;
    int realN = (N == 256) ? 240 : N;
    unsigned short* d = dst + (size_t)n * Kpad;
    for (int k = threadIdx.x; k < Kpad; k += 64)
        d[k] = f2bf((k < K && n < realN) ? src[(size_t)k * realN + n] : 0.f);
}

// ---------------- MFMA GEMM: C = A[M,Kpad]bf16 @ Bt[N,Kpad]bf16 --------------
// tile 128x64, 4 waves (2x2), K-step 32. Staging via global_load_lds.
// Optional K-split via gridDim.z (flags&2 path -> atomicAdd). Bias by z==0.
// flags: 1 relu, 2 accumulate fp32 C, 4 QKV-packed epilogue, 8 bf16 out
__global__ __launch_bounds__(256)
void gemm_mfma(const unsigned short* __restrict__ A,
               const unsigned short* __restrict__ Bt,
               const float* __restrict__ bias,
               float* __restrict__ C, unsigned short* __restrict__ Cbf,
               unsigned short* __restrict__ qp, unsigned short* __restrict__ kp,
               unsigned short* __restrict__ vp,
               int M, int N, int Kpad, int Cstride, int flags)
{
    __shared__ __align__(16) unsigned short As[128 * 32];   // 8 KB
    __shared__ __align__(16) unsigned short Bs[64 * 32];    // 4 KB
    const int tid = threadIdx.x;
    const int bm = blockIdx.x * 128;
    const int bn = blockIdx.y * 64;
    const int zs = gridDim.z, zi = blockIdx.z;
    const int wave = tid >> 6, lane = tid & 63;
    const int wm = (wave & 1) * 64, wn = (wave >> 1) * 32;
    const int lq = lane >> 4, lr = lane & 15;

    f32x4 acc[4][2];
    #pragma unroll
    for (int i = 0; i < 4; i++)
        #pragma unroll
        for (int j = 0; j < 2; j++) acc[i][j] = (f32x4){0.f, 0.f, 0.f, 0.f};

    const int srow = lane >> 2;            // 0..15
    const int schk = (lane & 3) << 3;      // 0,8,16,24
    const int nkt = Kpad >> 5;
    const int kt0 = (nkt * zi) / zs;
    const int kt1 = (nkt * (zi + 1)) / zs;

    const unsigned short* ga0 = A + (size_t)(bm + wave * 32 + srow) * Kpad + schk + kt0 * 32;
    const unsigned short* ga1 = A + (size_t)(bm + wave * 32 + 16 + srow) * Kpad + schk + kt0 * 32;
    const unsigned short* gb  = Bt + (size_t)(bn + wave * 16 + srow) * Kpad + schk + kt0 * 32;
    char* la0 = (char*)As + wave * 2048;
    char* la1 = (char*)As + wave * 2048 + 1024;
    char* lb  = (char*)Bs + wave * 1024;

    for (int kt = kt0; kt < kt1; kt++) {
        gl2lds16(ga0, la0);
        gl2lds16(ga1, la1);
        gl2lds16(gb, lb);
        ga0 += 32; ga1 += 32; gb += 32;
        __syncthreads();
        bf16x8 af[4], bfr[2];
        #pragma unroll
        for (int i = 0; i < 4; i++)
            af[i] = *(const bf16x8*)&As[(wm + i * 16 + lr) * 32 + lq * 8];
        #pragma unroll
        for (int j = 0; j < 2; j++)
            bfr[j] = *(const bf16x8*)&Bs[(wn + j * 16 + lr) * 32 + lq * 8];
        #pragma unroll
        for (int i = 0; i < 4; i++)
            #pragma unroll
            for (int j = 0; j < 2; j++)
                acc[i][j] = __builtin_amdgcn_mfma_f32_16x16x32_bf16(af[i], bfr[j], acc[i][j], 0, 0, 0);
        __syncthreads();
    }

    if (flags & 4) {                       // QKV packed epilogue (N=720)
        #pragma unroll
        for (int j = 0; j < 2; j++) {
            int n = bn + wn + j * 16 + lr;
            if (n >= N) continue;
            int which = n / 240;
            int rem = n - which * 240;
            int hh = rem / 15;
            int c = rem - hh * 15;
            unsigned short* dst = (which == 0) ? qp : (which == 1) ? kp : vp;
            float bias_n = bias[n];
            float mult = (which == 0) ? (SCALE_ * LOG2E_) : 1.f;
            #pragma unroll
            for (int i = 0; i < 4; i++)
                #pragma unroll
                for (int r = 0; r < 4; r++) {
                    int m = bm + wm + i * 16 + lq * 4 + r;
                    if (m >= M) continue;
                    float s = (acc[i][j][r] + bias_n) * mult;
                    int b = m / LP_, l = m - b * LP_;
                    unsigned short bits = (which == 2) ? f2h(s) : f2bf(s);
                    dst[(((size_t)b * H_ + hh) * LP_ + l) * 16 + c] = bits;
                }
        }
    } else if (flags & 8) {                // bf16 output
        #pragma unroll
        for (int i = 0; i < 4; i++)
            #pragma unroll
            for (int j = 0; j < 2; j++) {
                int n = bn + wn + j * 16 + lr;
                if (n >= N) continue;
                float bias_n = bias ? bias[n] : 0.f;
                #pragma unroll
                for (int r = 0; r < 4; r++) {
                    int m = bm + wm + i * 16 + lq * 4 + r;
                    if (m >= M) continue;
                    float s = acc[i][j][r] + bias_n;
                    if (flags & 1) s = fmaxf(s, 0.f);
                    Cbf[(size_t)m * Cstride + n] = f2bf(s);
                }
            }
    } else {                               // fp32 output (optionally accumulate)
        #pragma unroll
        for (int i = 0; i < 4; i++)
            #pragma unroll
            for (int j = 0; j < 2; j++) {
                int n = bn + wn + j * 16 + lr;
                if (n >= N) continue;
                float bias_n = (bias && zi == 0) ? bias[n] : 0.f;
                #pragma unroll
                for (int r = 0; r < 4; r++) {
                    int m = bm + wm + i * 16 + lq * 4 + r;
                    if (m >= M) continue;
                    float s = acc[i][j][r] + bias_n;
                    if (flags & 1) s = fmaxf(s, 0.f);
                    size_t off = (size_t)m * Cstride + n;
                    if (flags & 2) {
                        if (zs > 1) atomicAdd(&C[off], s);
                        else C[off] += s;
                    } else C[off] = s;
                }
            }
    }
}

// ------------- LN240: wave-per-row, fp32 in -> bf16 out [rows][256] ----------
__global__ __launch_bounds__(256)
void ln240(const float* __restrict__ in, unsigned short* __restrict__ out,
           const float* __restrict__ g, const float* __restrict__ bb) {
    const int row = blockIdx.x * 4 + (threadIdx.x >> 6);
    const int lane = threadIdx.x & 63;
    const float* x = in + (size_t)row * 240;
    float4 v = {0.f, 0.f, 0.f, 0.f};
    if (lane < 60) v = *(const float4*)(x + lane * 4);
    float s = (v.x + v.y) + (v.z + v.w);
    #pragma unroll
    for (int off = 32; off; off >>= 1) s += __shfl_xor(s, off);
    const float mean = s * (1.f / 240.f);
    float4 d;
    d.x = v.x - mean; d.y = v.y - mean; d.z = v.z - mean; d.w = v.w - mean;
    float vs = (lane < 60) ? (d.x * d.x + d.y * d.y) + (d.z * d.z + d.w * d.w) : 0.f;
    #pragma unroll
    for (int off = 32; off; off >>= 1) vs += __shfl_xor(vs, off);
    const float rs = rsqrtf(vs * (1.f / 240.f) + 1e-5f);
    ushort4 o4 = {0, 0, 0, 0};
    if (lane < 60) {
        float4 g4 = *(const float4*)(g + lane * 4);
        float4 b4 = *(const float4*)(bb + lane * 4);
        o4.x = f2bf(d.x * rs * g4.x + b4.x);
        o4.y = f2bf(d.y * rs * g4.y + b4.y);
        o4.z = f2bf(d.z * rs * g4.z + b4.z);
        o4.w = f2bf(d.w * rs * g4.w + b4.w);
    }
    *(ushort4*)(out + (size_t)row * 256 + lane * 4) = o4;   // lanes 60..63: pad zeros
}

// ------------- LN480+relu: wave-per-row, fp32 in -> bf16 out [rows][480] -----
__global__ __launch_bounds__(256)
void ln480(const float* __restrict__ in, unsigned short* __restrict__ out,
           const float* __restrict__ g, const float* __restrict__ bb) {
    const int row = blockIdx.x * 4 + (threadIdx.x >> 6);
    const int lane = threadIdx.x & 63;
    const float* x = in + (size_t)row * 480;
    float4 va = {0.f,0.f,0.f,0.f}, vb = {0.f,0.f,0.f,0.f};
    if (lane < 60) {
        va = *(const float4*)(x + lane * 8);
        vb = *(const float4*)(x + lane * 8 + 4);
    }
    float s = ((va.x + va.y) + (va.z + va.w)) + ((vb.x + vb.y) + (vb.z + vb.w));
    #pragma unroll
    for (int off = 32; off; off >>= 1) s += __shfl_xor(s, off);
    const float mean = s * (1.f / 480.f);
    float4 da, db;
    da.x = va.x - mean; da.y = va.y - mean; da.z = va.z - mean; da.w = va.w - mean;
    db.x = vb.x - mean; db.y = vb.y - mean; db.z = vb.z - mean; db.w = vb.w - mean;
    float vs = (lane < 60) ? ((da.x*da.x + da.y*da.y) + (da.z*da.z + da.w*da.w)) +
                             ((db.x*db.x + db.y*db.y) + (db.z*db.z + db.w*db.w)) : 0.f;
    #pragma unroll
    for (int off = 32; off; off >>= 1) vs += __shfl_xor(vs, off);
    const float rs = rsqrtf(vs * (1.f / 480.f) + 1e-5f);
    if (lane < 60) {
        float4 ga = *(const float4*)(g + lane * 8);
        float4 gb = *(const float4*)(g + lane * 8 + 4);
        float4 ba = *(const float4*)(bb + lane * 8);
        float4 b2 = *(const float4*)(bb + lane * 8 + 4);
        ushort4 oa, ob;
        oa.x = f2bf(fmaxf(da.x * rs * ga.x + ba.x, 0.f));
        oa.y = f2bf(fmaxf(da.y * rs * ga.y + ba.y, 0.f));
        oa.z = f2bf(fmaxf(da.z * rs * ga.z + ba.z, 0.f));
        oa.w = f2bf(fmaxf(da.w * rs * ga.w + ba.w, 0.f));
        ob.x = f2bf(fmaxf(db.x * rs * gb.x + b2.x, 0.f));
        ob.y = f2bf(fmaxf(db.y * rs * gb.y + b2.y, 0.f));
        ob.z = f2bf(fmaxf(db.z * rs * gb.z + b2.z, 0.f));
        ob.w = f2bf(fmaxf(db.w * rs * gb.w + b2.w, 0.f));
        *(ushort4*)(out + (size_t)row * 480 + lane * 8) = oa;
        *(ushort4*)(out + (size_t)row * 480 + lane * 8 + 4) = ob;
    }
}

// -------- embed finish: wave-per-row LN(g2)+relu+pos (cls for l==0),
// then layer-0 ln1 of the same row in-register -> ybf. lanes 60..62 also
// write q/k/v col-15 constants (replaces attn_init).
__global__ __launch_bounds__(256)
void embed_finish(const float* __restrict__ tmp, const float* __restrict__ mask,
                  const float* __restrict__ g, const float* __restrict__ bb,
                  const float* __restrict__ pos, const float* __restrict__ cls,
                  const float* __restrict__ l1g, const float* __restrict__ l1b,
                  float* __restrict__ h, unsigned short* __restrict__ ybf,
                  unsigned short* __restrict__ qp, unsigned short* __restrict__ kp,
                  unsigned short* __restrict__ vp) {
    const int row = blockIdx.x * 4 + (threadIdx.x >> 6);
    const int lane = threadIdx.x & 63;
    const int b = row / LP_, l = row - b * LP_;
    float* outr = h + (size_t)row * 240;

    if (lane >= 60 && lane <= 62) {
        unsigned short bits;
        unsigned short* dst;
        if (lane == 60) { bits = f2bf(LOG2E_); dst = qp; }
        else if (lane == 61) { bits = (mask[row] != 0.f) ? f2bf(-10000.f) : 0; dst = kp; }
        else { bits = f2h(1.f); dst = vp; }
        #pragma unroll
        for (int hh = 0; hh < H_; hh++)
            dst[(((size_t)b * H_ + hh) * LP_ + l) * 16 + 15] = bits;
    }

    float4 o = {0.f, 0.f, 0.f, 0.f};
    if (l == 0) {
        if (lane < 60) o = *(const float4*)(cls + lane * 4);
    } else {
        const float* x = tmp + ((size_t)b * L_ + (l - 1)) * 240;
        float4 v = {0.f, 0.f, 0.f, 0.f};
        if (lane < 60) v = *(const float4*)(x + lane * 4);
        float s = (v.x + v.y) + (v.z + v.w);
        #pragma unroll
        for (int off = 32; off; off >>= 1) s += __shfl_xor(s, off);
        const float mean = s * (1.f / 240.f);
        float4 d;
        d.x = v.x - mean; d.y = v.y - mean; d.z = v.z - mean; d.w = v.w - mean;
        float vs = (lane < 60) ? (d.x * d.x + d.y * d.y) + (d.z * d.z + d.w * d.w) : 0.f;
        #pragma unroll
        for (int off = 32; off; off >>= 1) vs += __shfl_xor(vs, off);
        const float rs = rsqrtf(vs * (1.f / 240.f) + 1e-5f);
        if (lane < 60) {
            float4 g4 = *(const float4*)(g + lane * 4);
            float4 b4 = *(const float4*)(bb + lane * 4);
            float4 p4 = *(const float4*)(pos + (size_t)(l - 1) * 240 + lane * 4);
            o.x = fmaxf(d.x * rs * g4.x + b4.x, 0.f) + p4.x;
            o.y = fmaxf(d.y * rs * g4.y + b4.y, 0.f) + p4.y;
            o.z = fmaxf(d.z * rs * g4.z + b4.z, 0.f) + p4.z;
            o.w = fmaxf(d.w * rs * g4.w + b4.w, 0.f) + p4.w;
        }
    }
    if (lane < 60) *(float4*)(outr + lane * 4) = o;

    // ---- layer-0 ln1 of this row (value already in registers) ----
    float s1 = (o.x + o.y) + (o.z + o.w);
    #pragma unroll
    for (int off = 32; off; off >>= 1) s1 += __shfl_xor(s1, off);
    const float mean1 = s1 * (1.f / 240.f);
    float4 d1;
    d1.x = o.x - mean1; d1.y = o.y - mean1; d1.z = o.z - mean1; d1.w = o.w - mean1;
    float vs1 = (lane < 60) ? (d1.x * d1.x + d1.y * d1.y) + (d1.z * d1.z + d1.w * d1.w) : 0.f;
    #pragma unroll
    for (int off = 32; off; off >>= 1) vs1 += __shfl_xor(vs1, off);
    const float rs1 = rsqrtf(vs1 * (1.f / 240.f) + 1e-5f);
    ushort4 o4 = {0, 0, 0, 0};
    if (lane < 60) {
        float4 g4 = *(const float4*)(l1g + lane * 4);
        float4 b4 = *(const float4*)(l1b + lane * 4);
        o4.x = f2bf(d1.x * rs1 * g4.x + b4.x);
        o4.y = f2bf(d1.y * rs1 * g4.y + b4.y);
        o4.z = f2bf(d1.z * rs1 * g4.z + b4.z);
        o4.w = f2bf(d1.w * rs1 * g4.w + b4.w);
    }
    *(ushort4*)(ybf + (size_t)row * 256 + lane * 4) = o4;
}

// ---------------- MFMA flash attention: block per (b,h), 4 waves -------------
__global__ __launch_bounds__(256)
void attn_mfma(const unsigned short* __restrict__ qp, const unsigned short* __restrict__ kp,
               const unsigned short* __restrict__ vp, unsigned short* __restrict__ obf)
{
    __shared__ __align__(16) unsigned short Kl[KP_ * 24];    // 13.5 KB
    __shared__ __align__(16) unsigned short Vt[16 * 296];    // 9.25 KB  V^T f16
    __shared__ __align__(16) unsigned short Pl[4][16 * 296]; // 37 KB    P f16 per wave
    const int hh = blockIdx.x, b = blockIdx.y;
    const int tid = threadIdx.x;
    const int wave = tid >> 6, lane = tid & 63;
    const int lq = lane >> 4, lr = lane & 15;
    const size_t base = ((size_t)b * H_ + hh) * LP_ * 16;

    for (int key = tid; key < KP_; key += 256) {
        uint4 z = {0u, 0u, 0u, 0u};
        uint4 k0 = z, k1 = z, v0 = z, v1 = z;
        if (key < LP_) {
            k0 = *(const uint4*)(kp + base + (size_t)key * 16);
            k1 = *(const uint4*)(kp + base + (size_t)key * 16 + 8);
            v0 = *(const uint4*)(vp + base + (size_t)key * 16);
            v1 = *(const uint4*)(vp + base + (size_t)key * 16 + 8);
        } else {
            k1.w = 0xC61C0000u;            // elem15 = bf16(-10000) sentinel
        }
        *(uint4*)&Kl[key * 24] = k0;
        *(uint4*)&Kl[key * 24 + 8] = k1;
        unsigned short vs[8];
        *(uint4*)vs = v0;
        #pragma unroll
        for (int d = 0; d < 8; d++) Vt[d * 296 + key] = vs[d];
        *(uint4*)vs = v1;
        #pragma unroll
        for (int d = 0; d < 8; d++) Vt[(d + 8) * 296 + key] = vs[d];
    }
    __syncthreads();

    unsigned short* Pw = &Pl[wave][0];
    for (int qt = wave; qt < 17; qt += 4) {
        const int qrow = qt * 16 + lr;
        bf16x8 aq = {0, 0, 0, 0, 0, 0, 0, 0};
        if (lq < 2)
            aq = *(const bf16x8*)(qp + base + (size_t)qrow * 16 + lq * 8);
        for (int kt = 0; kt < 18; kt++) {
            bf16x8 bk = {0, 0, 0, 0, 0, 0, 0, 0};
            if (lq < 2)
                bk = *(const bf16x8*)&Kl[(kt * 16 + lr) * 24 + lq * 8];
            f32x4 sacc = {0.f, 0.f, 0.f, 0.f};
            sacc = __builtin_amdgcn_mfma_f32_16x16x32_bf16(aq, bk, sacc, 0, 0, 0);
            #pragma unroll
            for (int r = 0; r < 4; r++)
                Pw[(lq * 4 + r) * 296 + kt * 16 + lr] = f2h(exp2f(sacc[r]));
        }
        asm volatile("s_waitcnt lgkmcnt(0)" ::: "memory");
        f32x4 o = {0.f, 0.f, 0.f, 0.f};
        #pragma unroll
        for (int ks = 0; ks < 9; ks++) {
            f16x8 ap = *(const f16x8*)&Pw[lr * 296 + ks * 32 + lq * 8];
            f16x8 bv = *(const f16x8*)&Vt[lr * 296 + ks * 32 + lq * 8];
            o = __builtin_amdgcn_mfma_f32_16x16x32_f16(ap, bv, o, 0, 0, 0);
        }
        asm volatile("s_waitcnt lgkmcnt(0)" ::: "memory");
        #pragma unroll
        for (int r = 0; r < 4; r++) {
            float denom = __shfl(o[r], lane | 15);
            int q = qt * 16 + lq * 4 + r;
            if (q < LP_ && lr < 15)
                obf[((size_t)b * LP_ + q) * 256 + hh * DK_ + lr] = f2bf(o[r] / denom);
        }
    }
    // zero pad cols 240..255 (once per row, by hh==0 block)
    if (hh == 0) {
        for (int q = tid; q < LP_; q += 256) {
            uint4 z = {0u, 0u, 0u, 0u};
            *(uint4*)(obf + ((size_t)b * LP_ + q) * 256 + 240) = z;
            *(uint4*)(obf + ((size_t)b * LP_ + q) * 256 + 248) = z;
        }
    }
}

// ---------------- masked mean pool (partial) ---------------------------------
__global__ void pool_partial(const float* __restrict__ h, const float* __restrict__ mask,
                             float* __restrict__ partial) {
    int b = blockIdx.x, slice = blockIdx.y;
    int d = threadIdx.x;
    if (d >= D_) return;
    float s = 0.f;
    int l0 = slice * 29;
    for (int i = 0; i < 29; i++) {
        int l = l0 + i;
        if (l < LP_ && mask[b * LP_ + l] == 0.f)
            s += h[((size_t)b * LP_ + l) * D_ + d];
    }
    partial[((size_t)b * 9 + slice) * D_ + d] = s;
}

// ---------------- pool finalize + logits -------------------------------------
__global__ __launch_bounds__(256)
void pool_logits(const float* __restrict__ partial, const float* __restrict__ mask,
                 const float* __restrict__ W, const float* __restrict__ bias,
                 float* __restrict__ out) {
    int b = blockIdx.x;
    int t = threadIdx.x;
    __shared__ float red[256];
    __shared__ float pool[240];
    float c = 0.f;
    for (int l = t; l < LP_; l += 256) c += (mask[b * LP_ + l] == 0.f) ? 1.f : 0.f;
    red[t] = c;
    __syncthreads();
    for (int off = 128; off > 0; off >>= 1) {
        if (t < off) red[t] += red[t + off];
        __syncthreads();
    }
    float inv = 1.f / red[0];
    if (t < D_) {
        float s = 0.f;
        #pragma unroll
        for (int sl = 0; sl < 9; sl++) s += partial[((size_t)b * 9 + sl) * D_ + t];
        pool[t] = s * inv;
    }
    __syncthreads();
    if (t < NC_) {
        float s = bias[t];
        for (int kk = 0; kk < D_; kk++) s += pool[kk] * W[(size_t)kk * NC_ + t];
        out[b * NC_ + t] = s;
    }
}

extern "C" void kernel_launch(void* const* d_in, const int* in_sizes, int n_in,
                              void* d_out, int out_size, void* d_ws, size_t ws_size,
                              hipStream_t stream) {
    const float* x        = (const float*)d_in[0];
    const float* pos      = (const float*)d_in[1];
    const float* cls      = (const float*)d_in[2];
    const float* e_W1     = (const float*)d_in[3];
    const float* e_b1     = (const float*)d_in[4];
    const float* e_g1     = (const float*)d_in[5];
    const float* e_bn1    = (const float*)d_in[6];
    const float* e_W2     = (const float*)d_in[7];
    const float* e_b2     = (const float*)d_in[8];
    const float* e_g2     = (const float*)d_in[9];
    const float* e_bn2    = (const float*)d_in[10];
    const float* ln1_g    = (const float*)d_in[11];
    const float* ln1_b    = (const float*)d_in[12];
    const float* Wq       = (const float*)d_in[13];
    const float* bq       = (const float*)d_in[14];
    const float* Wk       = (const float*)d_in[15];
    const float* bk       = (const float*)d_in[16];
    const float* Wv       = (const float*)d_in[17];
    const float* bv       = (const float*)d_in[18];
    const float* Wo       = (const float*)d_in[19];
    const float* bo       = (const float*)d_in[20];
    const float* ln2_g    = (const float*)d_in[21];
    const float* ln2_b    = (const float*)d_in[22];
    const float* W1       = (const float*)d_in[23];
    const float* b1       = (const float*)d_in[24];
    const float* W2       = (const float*)d_in[25];
    const float* b2       = (const float*)d_in[26];
    const float* logit_W  = (const float*)d_in[27];
    const float* logit_b  = (const float*)d_in[28];
    float* out = (float*)d_out;

    const size_t TOK  = (size_t)B_ * LP_;            // 8224
    const size_t TOKP = 8320;                        // padded to 65*128
    const size_t HN   = TOK * D_;
    const size_t QN   = (size_t)B_ * H_ * LP_ * 16;  // 2,105,344

    char* wsb = (char*)d_ws;
    size_t cur = 0;
    auto take = [&](size_t bytes) { void* p = wsb + cur; cur += (bytes + 15) & ~15ULL; return p; };
    float* mask = (float*)take(8224 * 4);
    float* h    = (float*)take(HN * 4);
    float* b720 = (float*)take(NB_ * 720 * 4);
    float* part = (float*)take((size_t)B_ * 9 * D_ * 4);
    void* regionA = take((size_t)8192 * 480 * 4);
    float* tmp1 = (float*)regionA;
    unsigned short* tbf = (unsigned short*)regionA;
    void* regionB = take(TOKP * 256 * 2 * 2);
    float* y32 = (float*)regionB;
    unsigned short* ybf = (unsigned short*)regionB;
    unsigned short* obf = ybf + TOKP * 256;
    unsigned short* xbf  = (unsigned short*)take((size_t)8192 * 192 * 2);
    unsigned short* We1  = (unsigned short*)take((size_t)512 * 192 * 2);
    unsigned short* We2  = (unsigned short*)take((size_t)256 * 480 * 2);
    unsigned short* Wqkv = (unsigned short*)take((size_t)NB_ * 768 * 256 * 2);
    unsigned short* WoT  = (unsigned short*)take((size_t)NB_ * 256 * 256 * 2);
    unsigned short* W1T  = (unsigned short*)take((size_t)NB_ * 512 * 256 * 2);
    unsigned short* W2T  = (unsigned short*)take((size_t)NB_ * 256 * 480 * 2);
    unsigned short* qp = (unsigned short*)take(QN * 3 * 2 + 16 * 16 * 2);
    unsigned short* kp = qp + QN;
    unsigned short* vp = kp + QN;
    unsigned short* t480bf = qp;   // aliases qp/kp, dead before embed_finish

    const int BS = 256;

    // zero y32 so embed gemm2 can K-split accumulate (regionB untouched yet)
    hipMemsetAsync(y32, 0, (size_t)8192 * 240 * 4, stream);

    // prep (2 dispatches)
    prep_misc<<<8192 + NB_ + 129, 64, 0, stream>>>(x, xbf, bq, bk, bv, b720, mask);
    prep_weights<<<dim3(480, 38), 64, 0, stream>>>(e_W1, e_W2, Wq, Wk, Wv, Wo, W1, W2,
                                                   We1, We2, Wqkv, WoT, W1T, W2T);

    // embed
    gemm_mfma<<<dim3(64, 8), BS, 0, stream>>>(xbf, We1, e_b1, tmp1, nullptr,
                                              nullptr, nullptr, nullptr,
                                              8192, 480, 192, 480, 0);
    ln480<<<2048, BS, 0, stream>>>(tmp1, t480bf, e_g1, e_bn1);
    gemm_mfma<<<dim3(64, 4, 2), BS, 0, stream>>>(t480bf, We2, e_b2, y32, nullptr,
                                                 nullptr, nullptr, nullptr,
                                                 8192, 240, 480, 240, 2);
    embed_finish<<<(int)(TOK / 4), BS, 0, stream>>>(y32, mask, e_g2, e_bn2, pos, cls,
                                                    ln1_g, ln1_b, h, ybf, qp, kp, vp);

    for (int i = 0; i < NB_; i++) {
        gemm_mfma<<<dim3(65, 12), BS, 0, stream>>>(ybf, Wqkv + (size_t)i * 768 * 256,
                                                   b720 + i * 720, nullptr, nullptr,
                                                   qp, kp, vp,
                                                   (int)TOK, 720, 256, 0, 4);
        attn_mfma<<<dim3(H_, B_), BS, 0, stream>>>(qp, kp, vp, obf);
        gemm_mfma<<<dim3(65, 4, 2), BS, 0, stream>>>(obf, WoT + (size_t)i * 256 * 256,
                                                     bo + i * D_, h, nullptr,
                                                     nullptr, nullptr, nullptr,
                                                     (int)TOK, 240, 256, 240, 2);
        ln240<<<(int)(TOK / 4), BS, 0, stream>>>(h, ybf, ln2_g + i * D_, ln2_b + i * D_);
        gemm_mfma<<<dim3(65, 8), BS, 0, stream>>>(ybf, W1T + (size_t)i * 512 * 256,
                                                  b1 + i * HID_, nullptr, tbf,
                                                  nullptr, nullptr, nullptr,
                                                  (int)TOK, 480, 256, 480, 1 | 8);
        gemm_mfma<<<dim3(65, 4, 2), BS, 0, stream>>>(tbf, W2T + (size_t)i * 256 * 480,
                                                     b2 + i * D_, h, nullptr,
                                                     nullptr, nullptr, nullptr,
                                                     (int)TOK, 240, 480, 240, 2);
        if (i < NB_ - 1)
            ln240<<<(int)(TOK / 4), BS, 0, stream>>>(h, ybf,
                                                     ln1_g + (i + 1) * D_,
                                                     ln1_b + (i + 1) * D_);
    }

    pool_partial<<<dim3(B_, 9), BS, 0, stream>>>(h, mask, part);
    pool_logits<<<B_, BS, 0, stream>>>(part, mask, logit_W, logit_b, out);
}